// Round 7
// baseline (155.807 us; speedup 1.0000x reference)
//
#include <hip/hip_runtime.h>

#define NTOKEN 200000
#define NINP   64
#define NEDGE  2000000
#define NBL    12800
#define NBKT   512
#define NPB    391            // nodes per bucket
#define CHUNK  4096
#define NCHUNK ((NEDGE + CHUNK - 1) / CHUNK)   // 489
#define CAP    6144

typedef unsigned short ushortT;

// bf16 <-> fp32 bit tricks
#define B2F(h) __uint_as_float(((unsigned)(h)) << 16)
__device__ __forceinline__ ushortT f2b(float x) {
    unsigned u = __float_as_uint(x);
    return (ushortT)((u + 0x7FFFu + ((u >> 16) & 1u)) >> 16);   // RNE
}

// ---- inclusive scan of s[0..511] with 256 threads; p is 256-int temp ----
__device__ __forceinline__ void scan512(int* s, int* p) {
    int t = threadIdx.x;
    int a = s[2 * t], b = s[2 * t + 1];
    p[t] = a + b;
    __syncthreads();
    for (int d = 1; d < 256; d <<= 1) {
        int v = (t >= d) ? p[t - d] : 0;
        __syncthreads();
        p[t] += v;
        __syncthreads();
    }
    int incl = p[t];
    s[2 * t + 1] = incl;
    s[2 * t]     = incl - b;
    __syncthreads();
}

// ---- fused: emb fp32->bf16 convert + zero counters/flags ----
__global__ void k_prep(const float* __restrict__ emb, ushortT* __restrict__ embH,
                       int* __restrict__ bCnt, unsigned char* __restrict__ mark,
                       int* __restrict__ ncnt) {
    int id = blockIdx.x * blockDim.x + threadIdx.x;
    if (id < NTOKEN * NINP / 4) {
        float4 v = ((const float4*)emb)[id];
        ushort4 h;
        h.x = f2b(v.x); h.y = f2b(v.y); h.z = f2b(v.z); h.w = f2b(v.w);
        ((ushort4*)embH)[id] = h;
    }
    if (id < NBKT) bCnt[id] = 0;
    if (id < NTOKEN) mark[id] = 0;
    if (id == 0) *ncnt = 0;
}

// ---- pass A: bucket histogram, LDS pre-aggregated ----
__global__ void k_hist(const int* __restrict__ dst, int* __restrict__ bCnt) {
    __shared__ int h[NBKT];
    int t = threadIdx.x;
    h[t] = 0; h[t + 256] = 0;
    __syncthreads();
    for (int e = blockIdx.x * blockDim.x + t; e < NEDGE; e += gridDim.x * blockDim.x)
        atomicAdd(&h[(unsigned)dst[e] / NPB], 1);
    __syncthreads();
    if (h[t])       atomicAdd(&bCnt[t], h[t]);
    if (h[t + 256]) atomicAdd(&bCnt[t + 256], h[t + 256]);
}

// ---- pass S: scan bucket counts ----
__global__ void k_scanB(const int* __restrict__ bCnt, int* __restrict__ bStart,
                        int* __restrict__ gCur) {
    __shared__ int buf[NBKT];
    int t = threadIdx.x;
    int v = bCnt[t];
    buf[t] = v;
    __syncthreads();
    for (int d = 1; d < NBKT; d <<= 1) {
        int add = (t >= d) ? buf[t - d] : 0;
        __syncthreads();
        buf[t] += add;
        __syncthreads();
    }
    bStart[t + 1] = buf[t];
    gCur[t] = buf[t] - v;
    if (t == 0) bStart[0] = 0;
}

// ---- pass B: chunked bucket scatter with coalesced writes ----
__global__ void k_bucket(const int* __restrict__ src, const int* __restrict__ dst,
                         int* __restrict__ gCur, int* __restrict__ E) {
    __shared__ int sv[CHUNK];
    __shared__ int gd[CHUNK];
    __shared__ int h[NBKT];
    __shared__ int loff[NBKT];
    __shared__ int gb[NBKT];
    __shared__ int cur[NBKT];
    __shared__ int p[256];
    int t = threadIdx.x;
    int base = blockIdx.x * CHUNK;
    int cnt = NEDGE - base; if (cnt > CHUNK) cnt = CHUNK;

    h[t] = 0; h[t + 256] = 0; cur[t] = 0; cur[t + 256] = 0;
    __syncthreads();
    for (int j = t; j < cnt; j += 256)
        atomicAdd(&h[(unsigned)dst[base + j] / NPB], 1);
    __syncthreads();
    loff[2 * t] = h[2 * t]; loff[2 * t + 1] = h[2 * t + 1];
    __syncthreads();
    scan512(loff, p);
    if (h[t])       gb[t]       = atomicAdd(&gCur[t],       h[t]);
    if (h[t + 256]) gb[t + 256] = atomicAdd(&gCur[t + 256], h[t + 256]);
    loff[t]       -= h[t];
    loff[t + 256] -= h[t + 256];
    __syncthreads();
    for (int j = t; j < cnt; j += 256) {
        unsigned d = (unsigned)dst[base + j];
        unsigned b = d / NPB;
        int packed = (int)(((d - b * NPB) << 18) | (unsigned)src[base + j]);
        int pl = atomicAdd(&cur[b], 1);
        int slot = loff[b] + pl;
        sv[slot] = packed;
        gd[slot] = gb[b] + pl;
    }
    __syncthreads();
    for (int j = t; j < cnt; j += 256)
        E[gd[j]] = sv[j];
}

// ---- pass C: per-bucket CSR build + dinv/end ----
__global__ void k_csr(const int* __restrict__ E, const int* __restrict__ bStart,
                      int* __restrict__ csr, float* __restrict__ dinv,
                      int* __restrict__ endArr) {
    __shared__ int eL[CAP];
    __shared__ int csrL[CAP];
    __shared__ int cnt[NBKT];
    __shared__ int off[NBKT];
    __shared__ int cur[NBKT];
    __shared__ int p[256];
    int t = threadIdx.x;
    int b = blockIdx.x;
    int base = bStart[b];
    int n = bStart[b + 1] - base;
    int nodes = NTOKEN - b * NPB; if (nodes > NPB) nodes = NPB;

    cnt[t] = 0; cnt[t + 256] = 0;
    __syncthreads();
    bool fits = (n <= CAP);
    if (fits) {
        for (int j = t; j < n; j += 256) {
            int v = E[base + j];
            eL[j] = v;
            atomicAdd(&cnt[v >> 18], 1);
        }
    } else {
        for (int j = t; j < n; j += 256)
            atomicAdd(&cnt[E[base + j] >> 18], 1);
    }
    __syncthreads();
    off[2 * t] = cnt[2 * t]; off[2 * t + 1] = cnt[2 * t + 1];
    __syncthreads();
    scan512(off, p);
    for (int i = t; i < nodes; i += 256) {
        dinv[b * NPB + i]   = rsqrtf((float)(cnt[i] + 1));
        endArr[b * NPB + i] = base + off[i];
    }
    cur[t] = off[t] - cnt[t];
    cur[t + 256] = off[t + 256] - cnt[t + 256];
    __syncthreads();
    if (fits) {
        for (int j = t; j < n; j += 256) {
            int v = eL[j];
            int pos = atomicAdd(&cur[v >> 18], 1);
            csrL[pos] = v & 0x3FFFF;
        }
        __syncthreads();
        for (int j = t; j < n; j += 256)
            csr[base + j] = csrL[j];
    } else {
        for (int j = t; j < n; j += 256) {
            int v = E[base + j];
            int pos = atomicAdd(&cur[v >> 18], 1);
            csr[base + pos] = v & 0x3FFFF;
        }
    }
}

// ---- mark needed nodes: wave per token, plain byte stores ----
__global__ void k_mark2(const int* __restrict__ inp, const int* __restrict__ endArr,
                        const int* __restrict__ csr, unsigned char* __restrict__ mark) {
    int t = blockIdx.x * 4 + (threadIdx.x >> 6);
    if (t >= NBL) return;
    int lane = threadIdx.x & 63;
    int n = inp[t];
    int b = (n > 0) ? endArr[n - 1] : 0;
    int f = endArr[n];
    if (lane == 0) mark[n] = 1;
    for (int e = b + lane; e < f; e += 64) mark[csr[e]] = 1;
}

// ---- compact marked nodes -> nlist ----
__global__ void k_compactL(const unsigned char* __restrict__ mark,
                           int* __restrict__ nlist, int* __restrict__ ncnt) {
    __shared__ int wbase[4];
    int t = threadIdx.x;
    int i = blockIdx.x * 256 + t;
    int m = (i < NTOKEN) ? (mark[i] ? 1 : 0) : 0;
    unsigned long long bal = __ballot(m);
    int w = t >> 6, lane = t & 63;
    int rank = __popcll(bal & ((1ull << lane) - 1ull));
    if (lane == 0) wbase[w] = __popcll(bal);
    __syncthreads();
    if (t == 0) {
        int s0 = wbase[0], s1 = wbase[1], s2 = wbase[2], s3 = wbase[3];
        int tot = s0 + s1 + s2 + s3;
        int base = tot ? atomicAdd(ncnt, tot) : 0;
        wbase[0] = base; wbase[1] = base + s0;
        wbase[2] = base + s0 + s1; wbase[3] = base + s0 + s1 + s2;
    }
    __syncthreads();
    if (m) nlist[wbase[w] + rank] = i;
}

// ---- per-node bf16 row gather; first edge batch passed in registers ----
__device__ __forceinline__ float node_gather(const ushortT* __restrict__ tab,
                                             const int* __restrict__ csr,
                                             const float* __restrict__ dinv,
                                             int b, int deg, int lane,
                                             int myE, float myW, float acc) {
    float a0 = acc, a1 = 0.f, a2 = 0.f, a3 = 0.f;
    int base = 0;
    while (true) {
        int m = deg - base; if (m > 64) m = 64;
        int e = 0;
        for (; e + 4 <= m; e += 4) {
            int   s0 = __shfl(myE, e),     s1 = __shfl(myE, e + 1);
            int   s2 = __shfl(myE, e + 2), s3 = __shfl(myE, e + 3);
            float w0 = __shfl(myW, e),     w1 = __shfl(myW, e + 1);
            float w2 = __shfl(myW, e + 2), w3 = __shfl(myW, e + 3);
            float v0 = B2F(tab[s0 * NINP + lane]);
            float v1 = B2F(tab[s1 * NINP + lane]);
            float v2 = B2F(tab[s2 * NINP + lane]);
            float v3 = B2F(tab[s3 * NINP + lane]);
            a0 += w0 * v0; a1 += w1 * v1; a2 += w2 * v2; a3 += w3 * v3;
        }
        for (; e < m; ++e) {
            int s0 = __shfl(myE, e); float w0 = __shfl(myW, e);
            a0 += w0 * B2F(tab[s0 * NINP + lane]);
        }
        base += 64;
        if (base >= deg) break;
        int mm = deg - base; if (mm > 64) mm = 64;
        myE = 0; myW = 0.f;
        if (lane < mm) { myE = csr[b + base + lane]; myW = dinv[myE]; }
    }
    return (a0 + a1) + (a2 + a3);
}

// ---- layer 1 gather: two nodes per wave iteration, heads prefetched ----
__global__ void k_gather1(const int* __restrict__ nlist, const int* __restrict__ ncnt,
                          const int* __restrict__ endArr, const int* __restrict__ csr,
                          const float* __restrict__ dinv, const ushortT* __restrict__ embH,
                          ushortT* __restrict__ P1H) {
    int lane = threadIdx.x & 63;
    int wid = blockIdx.x * (blockDim.x >> 6) + (threadIdx.x >> 6);
    int nw  = gridDim.x * (blockDim.x >> 6);
    int ncount = *ncnt;
    for (int p = wid; 2 * p < ncount; p += nw) {
        int i0 = nlist[2 * p];
        bool has1 = (2 * p + 1 < ncount);
        int i1 = has1 ? nlist[2 * p + 1] : i0;
        int b0 = (i0 > 0) ? endArr[i0 - 1] : 0;
        int d0 = endArr[i0] - b0;
        int b1 = (i1 > 0) ? endArr[i1 - 1] : 0;
        int d1 = has1 ? (endArr[i1] - b1) : 0;
        float di0 = dinv[i0];
        float di1 = dinv[i1];
        int m0 = d0 > 64 ? 64 : d0;
        int m1 = d1 > 64 ? 64 : d1;
        int e0 = 0; float w0 = 0.f;
        if (lane < m0) { e0 = csr[b0 + lane]; w0 = dinv[e0]; }
        int e1 = 0; float w1 = 0.f;
        if (lane < m1) { e1 = csr[b1 + lane]; w1 = dinv[e1]; }
        float self0 = di0 * B2F(embH[i0 * NINP + lane]);
        float self1 = di1 * B2F(embH[i1 * NINP + lane]);
        float r0 = node_gather(embH, csr, dinv, b0, d0, lane, e0, w0, self0);
        float r1 = node_gather(embH, csr, dinv, b1, d1, lane, e1, w1, self1);
        P1H[i0 * NINP + lane] = f2b(di0 * r0);
        if (has1) P1H[i1 * NINP + lane] = f2b(di1 * r1);
    }
}

// ---- fold weights ----
__global__ void k_w12(const float* __restrict__ W1, const float* __restrict__ W2,
                      const float* __restrict__ b1, float* __restrict__ W12,
                      float* __restrict__ bb) {
    int id = blockIdx.x * blockDim.x + threadIdx.x;
    if (id < 64 * 64) {
        int i = id >> 6, j = id & 63;
        float acc = 0.f;
        for (int k = 0; k < 128; ++k) acc += W1[i * 128 + k] * W2[k * 64 + j];
        W12[id] = acc;
    } else if (id < 64 * 64 + 64) {
        int j = id - 64 * 64;
        float acc = 0.f;
        for (int k = 0; k < 128; ++k) acc += b1[k] * W2[k * 64 + j];
        bb[j] = acc;
    }
}

// ---- final: layer-2 gather (8-way, bf16 P1) + 64x64 GEMM + biases ----
__global__ void k_final(const int* __restrict__ inp, const int* __restrict__ endArr,
                        const int* __restrict__ csr, const float* __restrict__ dinv,
                        const ushortT* __restrict__ P1H, const float* __restrict__ W12,
                        const float* __restrict__ bb, const float* __restrict__ b2,
                        float* __restrict__ out) {
    int t = blockIdx.x * 4 + (threadIdx.x >> 6);
    if (t >= NBL) return;
    int lane = threadIdx.x & 63;
    int n = inp[t];
    float dn = dinv[n];
    int b = (n > 0) ? endArr[n - 1] : 0;
    int deg = endArr[n] - b;
    float a0 = dn * B2F(P1H[n * NINP + lane]);
    float a1 = 0.f, a2 = 0.f, a3 = 0.f, a4 = 0.f, a5 = 0.f, a6 = 0.f, a7 = 0.f;
    float sS = dn;
    for (int base = 0; base < deg; base += 64) {
        int m = deg - base; if (m > 64) m = 64;
        int myE = 0; float myW = 0.f;
        if (lane < m) { myE = csr[b + base + lane]; myW = dinv[myE]; }
        int e = 0;
        for (; e + 8 <= m; e += 8) {
            int   s0 = __shfl(myE, e),     s1 = __shfl(myE, e + 1);
            int   s2 = __shfl(myE, e + 2), s3 = __shfl(myE, e + 3);
            int   s4 = __shfl(myE, e + 4), s5 = __shfl(myE, e + 5);
            int   s6 = __shfl(myE, e + 6), s7 = __shfl(myE, e + 7);
            float w0 = __shfl(myW, e),     w1 = __shfl(myW, e + 1);
            float w2 = __shfl(myW, e + 2), w3 = __shfl(myW, e + 3);
            float w4 = __shfl(myW, e + 4), w5 = __shfl(myW, e + 5);
            float w6 = __shfl(myW, e + 6), w7 = __shfl(myW, e + 7);
            float v0 = B2F(P1H[s0 * NINP + lane]), v1 = B2F(P1H[s1 * NINP + lane]);
            float v2 = B2F(P1H[s2 * NINP + lane]), v3 = B2F(P1H[s3 * NINP + lane]);
            float v4 = B2F(P1H[s4 * NINP + lane]), v5 = B2F(P1H[s5 * NINP + lane]);
            float v6 = B2F(P1H[s6 * NINP + lane]), v7 = B2F(P1H[s7 * NINP + lane]);
            a0 += w0 * v0; a1 += w1 * v1; a2 += w2 * v2; a3 += w3 * v3;
            a4 += w4 * v4; a5 += w5 * v5; a6 += w6 * v6; a7 += w7 * v7;
            sS += ((w0 + w1) + (w2 + w3)) + ((w4 + w5) + (w6 + w7));
        }
        for (; e + 4 <= m; e += 4) {
            int   s0 = __shfl(myE, e),     s1 = __shfl(myE, e + 1);
            int   s2 = __shfl(myE, e + 2), s3 = __shfl(myE, e + 3);
            float w0 = __shfl(myW, e),     w1 = __shfl(myW, e + 1);
            float w2 = __shfl(myW, e + 2), w3 = __shfl(myW, e + 3);
            float v0 = B2F(P1H[s0 * NINP + lane]), v1 = B2F(P1H[s1 * NINP + lane]);
            float v2 = B2F(P1H[s2 * NINP + lane]), v3 = B2F(P1H[s3 * NINP + lane]);
            a0 += w0 * v0; a1 += w1 * v1; a2 += w2 * v2; a3 += w3 * v3;
            sS += (w0 + w1) + (w2 + w3);
        }
        for (; e < m; ++e) {
            int s0 = __shfl(myE, e); float w0 = __shfl(myW, e);
            a0 += w0 * B2F(P1H[s0 * NINP + lane]);
            sS += w0;
        }
    }
    float p2 = dn * ((((a0 + a1) + (a2 + a3)) + ((a4 + a5) + (a6 + a7))));
    float acc = b2[lane] + dn * sS * bb[lane];
#pragma unroll
    for (int k = 0; k < 64; ++k)
        acc += __shfl(p2, k) * W12[k * 64 + lane];
    out[t * 64 + lane] = acc;
}

extern "C" void kernel_launch(void* const* d_in, const int* in_sizes, int n_in,
                              void* d_out, int out_size, void* d_ws, size_t ws_size,
                              hipStream_t stream) {
    const int*   inp  = (const int*)d_in[0];
    const int*   eidx = (const int*)d_in[3];
    const int*   esrc = eidx;
    const int*   edst = eidx + NEDGE;
    const float* emb  = (const float*)d_in[4];
    const float* W1   = (const float*)d_in[5];
    const float* b1   = (const float*)d_in[6];
    const float* W2   = (const float*)d_in[7];
    const float* b2   = (const float*)d_in[8];
    float* out = (float*)d_out;

    char* ws = (char*)d_ws;
    int*           bCnt   = (int*)(ws + 0);          // 2,048
    int*           bStart = (int*)(ws + 4096);       // 2,052
    int*           gCur   = (int*)(ws + 8192);       // 2,048
    int*           ncnt   = (int*)(ws + 12288);      // 4
    float*         dinv   = (float*)(ws + 16384);    // 800,000
    int*           endArr = (int*)(ws + 817152);     // 800,000
    unsigned char* mark   = (unsigned char*)(ws + 1617408); // 200,000
    int*           nlist  = (int*)(ws + 1817600);    // 800,000
    int*           E      = (int*)(ws + 2617600);    // 8,000,000
    int*           csr    = (int*)(ws + 10617600);   // 8,000,000
    float*         W12    = (float*)(ws + 18617600); // 16,384
    float*         bb     = (float*)(ws + 18633984); // 256
    ushortT*       embH   = (ushortT*)(ws + 18634240); // 25,600,000
    ushortT*       P1H    = (ushortT*)(ws + 44234240); // 25,600,000 (end ~69.8 MB)

    const int B = 256;

    k_prep  <<<(NTOKEN * NINP / 4 + B - 1) / B, B, 0, stream>>>(emb, embH, bCnt, mark, ncnt);
    k_w12   <<<(64 * 64 + 64 + B - 1) / B, B, 0, stream>>>(W1, W2, b1, W12, bb);
    k_hist  <<<1024, B, 0, stream>>>(edst, bCnt);
    k_scanB <<<1, NBKT, 0, stream>>>(bCnt, bStart, gCur);
    k_bucket<<<NCHUNK, B, 0, stream>>>(esrc, edst, gCur, E);
    k_csr   <<<NBKT, B, 0, stream>>>(E, bStart, csr, dinv, endArr);

    k_mark2   <<<(NBL + 3) / 4, B, 0, stream>>>(inp, endArr, csr, mark);
    k_compactL<<<(NTOKEN + B - 1) / B, B, 0, stream>>>(mark, nlist, ncnt);
    k_gather1 <<<2048, B, 0, stream>>>(nlist, ncnt, endArr, csr, dinv, embH, P1H);

    k_final <<<(NBL + 3) / 4, B, 0, stream>>>(inp, endArr, csr, dinv, P1H, W12, bb, b2, out);
}

// Round 8
// 155.641 us; speedup vs baseline: 1.0011x; 1.0011x over previous
//
#include <hip/hip_runtime.h>

#define NTOKEN 200000
#define NINP   64
#define NEDGE  2000000
#define NBL    12800
#define NBKT   512
#define NPB    391            // nodes per bucket
#define CHUNK  4096
#define NCHUNK ((NEDGE + CHUNK - 1) / CHUNK)   // 489
#define CAP    6144

typedef unsigned short ushortT;

#define B2F(h) __uint_as_float(((unsigned)(h)) << 16)
__device__ __forceinline__ ushortT f2b(float x) {
    unsigned u = __float_as_uint(x);
    return (ushortT)((u + 0x7FFFu + ((u >> 16) & 1u)) >> 16);   // RNE
}

// ---- inclusive scan of s[0..511] with 256 threads; p is 256-int temp ----
__device__ __forceinline__ void scan512(int* s, int* p) {
    int t = threadIdx.x;
    int a = s[2 * t], b = s[2 * t + 1];
    p[t] = a + b;
    __syncthreads();
    for (int d = 1; d < 256; d <<= 1) {
        int v = (t >= d) ? p[t - d] : 0;
        __syncthreads();
        p[t] += v;
        __syncthreads();
    }
    int incl = p[t];
    s[2 * t + 1] = incl;
    s[2 * t]     = incl - b;
    __syncthreads();
}

// ---- K1: emb fp32->bf16 convert; blocks<1024 also histogram dst buckets ----
__global__ void k_prep(const float* __restrict__ emb, ushortT* __restrict__ embH,
                       const int* __restrict__ dst, int* __restrict__ bCnt) {
    __shared__ int h[NBKT];
    int t = threadIdx.x;
    bool doHist = (blockIdx.x < 1024);
    if (doHist) { h[t] = 0; h[t + 256] = 0; }
    __syncthreads();
    int id = blockIdx.x * 256 + t;
    if (id < NTOKEN * NINP / 4) {
        float4 v = ((const float4*)emb)[id];
        ushort4 hh;
        hh.x = f2b(v.x); hh.y = f2b(v.y); hh.z = f2b(v.z); hh.w = f2b(v.w);
        ((ushort4*)embH)[id] = hh;
    }
    if (doHist) {
        for (int e = blockIdx.x * 256 + t; e < NEDGE; e += 1024 * 256)
            atomicAdd(&h[(unsigned)dst[e] / NPB], 1);
        __syncthreads();
        if (h[t])       atomicAdd(&bCnt[t], h[t]);
        if (h[t + 256]) atomicAdd(&bCnt[t + 256], h[t + 256]);
    }
}

// ---- K2: mark queried nodes (mark/need2 pre-zeroed by memset) ----
__global__ void k_mark(const int* __restrict__ inp, unsigned char* __restrict__ mark,
                       unsigned char* __restrict__ need2) {
    int t = blockIdx.x * blockDim.x + threadIdx.x;
    if (t < NBL) { int n = inp[t]; mark[n] = 1; need2[n] = 1; }
}

// ---- K3: block0 = bucket scan; blocks 1..9 = W12/bb weight fold (512 thr) ----
__global__ void k_scanB_w12(const int* __restrict__ bCnt, int* __restrict__ bStart,
                            int* __restrict__ gCur,
                            const float* __restrict__ W1, const float* __restrict__ W2,
                            const float* __restrict__ b1, float* __restrict__ W12,
                            float* __restrict__ bb) {
    if (blockIdx.x == 0) {
        __shared__ int buf[NBKT];
        int t = threadIdx.x;
        int v = bCnt[t];
        buf[t] = v;
        __syncthreads();
        for (int d = 1; d < NBKT; d <<= 1) {
            int add = (t >= d) ? buf[t - d] : 0;
            __syncthreads();
            buf[t] += add;
            __syncthreads();
        }
        bStart[t + 1] = buf[t];
        gCur[t] = buf[t] - v;
        if (t == 0) bStart[0] = 0;
    } else {
        int id = (blockIdx.x - 1) * 512 + threadIdx.x;
        if (id < 64 * 64) {
            int i = id >> 6, j = id & 63;
            float acc = 0.f;
            for (int k = 0; k < 128; ++k) acc += W1[i * 128 + k] * W2[k * 64 + j];
            W12[id] = acc;
        } else if (id < 64 * 64 + 64) {
            int j = id - 64 * 64;
            float acc = 0.f;
            for (int k = 0; k < 128; ++k) acc += b1[k] * W2[k * 64 + j];
            bb[j] = acc;
        }
    }
}

// ---- K4: chunked bucket scatter + need2 marking ----
__global__ void k_bucket(const int* __restrict__ src, const int* __restrict__ dst,
                         int* __restrict__ gCur, int* __restrict__ E,
                         const unsigned char* __restrict__ mark,
                         unsigned char* __restrict__ need2) {
    __shared__ int sv[CHUNK];
    __shared__ int gd[CHUNK];
    __shared__ int h[NBKT];
    __shared__ int loff[NBKT];
    __shared__ int gb[NBKT];
    __shared__ int cur[NBKT];
    __shared__ int p[256];
    int t = threadIdx.x;
    int base = blockIdx.x * CHUNK;
    int cnt = NEDGE - base; if (cnt > CHUNK) cnt = CHUNK;

    h[t] = 0; h[t + 256] = 0; cur[t] = 0; cur[t + 256] = 0;
    __syncthreads();
    for (int j = t; j < cnt; j += 256)
        atomicAdd(&h[(unsigned)dst[base + j] / NPB], 1);
    __syncthreads();
    loff[2 * t] = h[2 * t]; loff[2 * t + 1] = h[2 * t + 1];
    __syncthreads();
    scan512(loff, p);
    if (h[t])       gb[t]       = atomicAdd(&gCur[t],       h[t]);
    if (h[t + 256]) gb[t + 256] = atomicAdd(&gCur[t + 256], h[t + 256]);
    loff[t]       -= h[t];
    loff[t + 256] -= h[t + 256];
    __syncthreads();
    for (int j = t; j < cnt; j += 256) {
        unsigned d = (unsigned)dst[base + j];
        unsigned b = d / NPB;
        int s = src[base + j];
        if (mark[d]) need2[s] = 1;          // layer-2 frontier expansion, fused
        int packed = (int)(((d - b * NPB) << 18) | (unsigned)s);
        int pl = atomicAdd(&cur[b], 1);
        int slot = loff[b] + pl;
        sv[slot] = packed;
        gd[slot] = gb[b] + pl;
    }
    __syncthreads();
    for (int j = t; j < cnt; j += 256)
        E[gd[j]] = sv[j];
}

// ---- K5: per-bucket CSR (selective placement) + dinv/end + nlist compaction ----
__global__ void k_csr(const int* __restrict__ E, const int* __restrict__ bStart,
                      const unsigned char* __restrict__ need2,
                      int* __restrict__ csr, float* __restrict__ dinv,
                      int* __restrict__ endArr, int* __restrict__ nlist,
                      int* __restrict__ ncnt) {
    __shared__ int eL[CAP];
    __shared__ int csrL[CAP];
    __shared__ int cnt[NBKT];
    __shared__ int off[NBKT];
    __shared__ int cur[NBKT];
    __shared__ int p[256];
    __shared__ unsigned char n2[NPB];
    __shared__ int nl[NPB];
    __shared__ int lcnt, nbase;
    int t = threadIdx.x;
    int b = blockIdx.x;
    int base = bStart[b];
    int n = bStart[b + 1] - base;
    int nodes = NTOKEN - b * NPB; if (nodes > NPB) nodes = NPB;

    cnt[t] = 0; cnt[t + 256] = 0;
    if (t == 0) lcnt = 0;
    for (int i = t; i < nodes; i += 256) n2[i] = need2[b * NPB + i];
    __syncthreads();
    bool fits = (n <= CAP);
    if (fits) {
        for (int j = t; j < n; j += 256) {
            int v = E[base + j];
            eL[j] = v;
            atomicAdd(&cnt[v >> 18], 1);
        }
    } else {
        for (int j = t; j < n; j += 256)
            atomicAdd(&cnt[E[base + j] >> 18], 1);
    }
    __syncthreads();
    off[2 * t] = cnt[2 * t]; off[2 * t + 1] = cnt[2 * t + 1];
    __syncthreads();
    scan512(off, p);
    for (int i = t; i < nodes; i += 256) {
        dinv[b * NPB + i]   = rsqrtf((float)(cnt[i] + 1));
        endArr[b * NPB + i] = base + off[i];
        if (n2[i]) nl[atomicAdd(&lcnt, 1)] = b * NPB + i;
    }
    cur[t] = off[t] - cnt[t];
    cur[t + 256] = off[t + 256] - cnt[t + 256];
    __syncthreads();
    if (t == 0) nbase = lcnt ? atomicAdd(ncnt, lcnt) : 0;
    __syncthreads();
    for (int i = t; i < lcnt; i += 256) nlist[nbase + i] = nl[i];
    if (fits) {
        for (int j = t; j < n; j += 256) {
            int v = eL[j];
            int node = v >> 18;
            if (!n2[node]) continue;              // placement only for needed rows
            int pos = atomicAdd(&cur[node], 1);
            csrL[pos] = v & 0x3FFFF;
        }
        __syncthreads();
        for (int j = t; j < n; j += 256)
            csr[base + j] = csrL[j];
    } else {
        for (int j = t; j < n; j += 256) {
            int v = E[base + j];
            int node = v >> 18;
            if (!n2[node]) continue;
            int pos = atomicAdd(&cur[node], 1);
            csr[base + pos] = v & 0x3FFFF;
        }
    }
}

// ---- per-node bf16 row gather; first edge batch passed in registers ----
__device__ __forceinline__ float node_gather(const ushortT* __restrict__ tab,
                                             const int* __restrict__ csr,
                                             const float* __restrict__ dinv,
                                             int b, int deg, int lane,
                                             int myE, float myW, float acc) {
    float a0 = acc, a1 = 0.f, a2 = 0.f, a3 = 0.f;
    int base = 0;
    while (true) {
        int m = deg - base; if (m > 64) m = 64;
        int e = 0;
        for (; e + 4 <= m; e += 4) {
            int   s0 = __shfl(myE, e),     s1 = __shfl(myE, e + 1);
            int   s2 = __shfl(myE, e + 2), s3 = __shfl(myE, e + 3);
            float w0 = __shfl(myW, e),     w1 = __shfl(myW, e + 1);
            float w2 = __shfl(myW, e + 2), w3 = __shfl(myW, e + 3);
            float v0 = B2F(tab[s0 * NINP + lane]);
            float v1 = B2F(tab[s1 * NINP + lane]);
            float v2 = B2F(tab[s2 * NINP + lane]);
            float v3 = B2F(tab[s3 * NINP + lane]);
            a0 += w0 * v0; a1 += w1 * v1; a2 += w2 * v2; a3 += w3 * v3;
        }
        for (; e < m; ++e) {
            int s0 = __shfl(myE, e); float w0 = __shfl(myW, e);
            a0 += w0 * B2F(tab[s0 * NINP + lane]);
        }
        base += 64;
        if (base >= deg) break;
        int mm = deg - base; if (mm > 64) mm = 64;
        myE = 0; myW = 0.f;
        if (lane < mm) { myE = csr[b + base + lane]; myW = dinv[myE]; }
    }
    return (a0 + a1) + (a2 + a3);
}

// ---- K6: layer-1 gather, two nodes per wave iteration ----
__global__ void k_gather1(const int* __restrict__ nlist, const int* __restrict__ ncnt,
                          const int* __restrict__ endArr, const int* __restrict__ csr,
                          const float* __restrict__ dinv, const ushortT* __restrict__ embH,
                          ushortT* __restrict__ P1H) {
    int lane = threadIdx.x & 63;
    int wid = blockIdx.x * (blockDim.x >> 6) + (threadIdx.x >> 6);
    int nw  = gridDim.x * (blockDim.x >> 6);
    int ncount = *ncnt;
    for (int p = wid; 2 * p < ncount; p += nw) {
        int i0 = nlist[2 * p];
        bool has1 = (2 * p + 1 < ncount);
        int i1 = has1 ? nlist[2 * p + 1] : i0;
        int b0 = (i0 > 0) ? endArr[i0 - 1] : 0;
        int d0 = endArr[i0] - b0;
        int b1 = (i1 > 0) ? endArr[i1 - 1] : 0;
        int d1 = has1 ? (endArr[i1] - b1) : 0;
        float di0 = dinv[i0];
        float di1 = dinv[i1];
        int m0 = d0 > 64 ? 64 : d0;
        int m1 = d1 > 64 ? 64 : d1;
        int e0 = 0; float w0 = 0.f;
        if (lane < m0) { e0 = csr[b0 + lane]; w0 = dinv[e0]; }
        int e1 = 0; float w1 = 0.f;
        if (lane < m1) { e1 = csr[b1 + lane]; w1 = dinv[e1]; }
        float self0 = di0 * B2F(embH[i0 * NINP + lane]);
        float self1 = di1 * B2F(embH[i1 * NINP + lane]);
        float r0 = node_gather(embH, csr, dinv, b0, d0, lane, e0, w0, self0);
        float r1 = node_gather(embH, csr, dinv, b1, d1, lane, e1, w1, self1);
        P1H[i0 * NINP + lane] = f2b(di0 * r0);
        if (has1) P1H[i1 * NINP + lane] = f2b(di1 * r1);
    }
}

// ---- K7: final layer-2 gather (8-way) + 64x64 GEMM + biases ----
__global__ void k_final(const int* __restrict__ inp, const int* __restrict__ endArr,
                        const int* __restrict__ csr, const float* __restrict__ dinv,
                        const ushortT* __restrict__ P1H, const float* __restrict__ W12,
                        const float* __restrict__ bb, const float* __restrict__ b2,
                        float* __restrict__ out) {
    int t = blockIdx.x * 4 + (threadIdx.x >> 6);
    if (t >= NBL) return;
    int lane = threadIdx.x & 63;
    int n = inp[t];
    float dn = dinv[n];
    int b = (n > 0) ? endArr[n - 1] : 0;
    int deg = endArr[n] - b;
    float a0 = dn * B2F(P1H[n * NINP + lane]);
    float a1 = 0.f, a2 = 0.f, a3 = 0.f, a4 = 0.f, a5 = 0.f, a6 = 0.f, a7 = 0.f;
    float sS = dn;
    for (int base = 0; base < deg; base += 64) {
        int m = deg - base; if (m > 64) m = 64;
        int myE = 0; float myW = 0.f;
        if (lane < m) { myE = csr[b + base + lane]; myW = dinv[myE]; }
        int e = 0;
        for (; e + 8 <= m; e += 8) {
            int   s0 = __shfl(myE, e),     s1 = __shfl(myE, e + 1);
            int   s2 = __shfl(myE, e + 2), s3 = __shfl(myE, e + 3);
            int   s4 = __shfl(myE, e + 4), s5 = __shfl(myE, e + 5);
            int   s6 = __shfl(myE, e + 6), s7 = __shfl(myE, e + 7);
            float w0 = __shfl(myW, e),     w1 = __shfl(myW, e + 1);
            float w2 = __shfl(myW, e + 2), w3 = __shfl(myW, e + 3);
            float w4 = __shfl(myW, e + 4), w5 = __shfl(myW, e + 5);
            float w6 = __shfl(myW, e + 6), w7 = __shfl(myW, e + 7);
            float v0 = B2F(P1H[s0 * NINP + lane]), v1 = B2F(P1H[s1 * NINP + lane]);
            float v2 = B2F(P1H[s2 * NINP + lane]), v3 = B2F(P1H[s3 * NINP + lane]);
            float v4 = B2F(P1H[s4 * NINP + lane]), v5 = B2F(P1H[s5 * NINP + lane]);
            float v6 = B2F(P1H[s6 * NINP + lane]), v7 = B2F(P1H[s7 * NINP + lane]);
            a0 += w0 * v0; a1 += w1 * v1; a2 += w2 * v2; a3 += w3 * v3;
            a4 += w4 * v4; a5 += w5 * v5; a6 += w6 * v6; a7 += w7 * v7;
            sS += ((w0 + w1) + (w2 + w3)) + ((w4 + w5) + (w6 + w7));
        }
        for (; e + 4 <= m; e += 4) {
            int   s0 = __shfl(myE, e),     s1 = __shfl(myE, e + 1);
            int   s2 = __shfl(myE, e + 2), s3 = __shfl(myE, e + 3);
            float w0 = __shfl(myW, e),     w1 = __shfl(myW, e + 1);
            float w2 = __shfl(myW, e + 2), w3 = __shfl(myW, e + 3);
            float v0 = B2F(P1H[s0 * NINP + lane]), v1 = B2F(P1H[s1 * NINP + lane]);
            float v2 = B2F(P1H[s2 * NINP + lane]), v3 = B2F(P1H[s3 * NINP + lane]);
            a0 += w0 * v0; a1 += w1 * v1; a2 += w2 * v2; a3 += w3 * v3;
            sS += (w0 + w1) + (w2 + w3);
        }
        for (; e < m; ++e) {
            int s0 = __shfl(myE, e); float w0 = __shfl(myW, e);
            a0 += w0 * B2F(P1H[s0 * NINP + lane]);
            sS += w0;
        }
    }
    float p2 = dn * ((((a0 + a1) + (a2 + a3)) + ((a4 + a5) + (a6 + a7))));
    float acc = b2[lane] + dn * sS * bb[lane];
#pragma unroll
    for (int k = 0; k < 64; ++k)
        acc += __shfl(p2, k) * W12[k * 64 + lane];
    out[t * 64 + lane] = acc;
}

extern "C" void kernel_launch(void* const* d_in, const int* in_sizes, int n_in,
                              void* d_out, int out_size, void* d_ws, size_t ws_size,
                              hipStream_t stream) {
    const int*   inp  = (const int*)d_in[0];
    const int*   eidx = (const int*)d_in[3];
    const int*   esrc = eidx;
    const int*   edst = eidx + NEDGE;
    const float* emb  = (const float*)d_in[4];
    const float* W1   = (const float*)d_in[5];
    const float* b1   = (const float*)d_in[6];
    const float* W2   = (const float*)d_in[7];
    const float* b2   = (const float*)d_in[8];
    float* out = (float*)d_out;

    char* ws = (char*)d_ws;
    int*           bCnt   = (int*)(ws + 0);            //     2,048
    int*           ncnt   = (int*)(ws + 2048);         //         4
    unsigned char* mark   = (unsigned char*)(ws + 4096);      // 200,000
    unsigned char* need2  = (unsigned char*)(ws + 204096);    // 200,000
    int*           bStart = (int*)(ws + 404224);       //     2,052
    int*           gCur   = (int*)(ws + 406528);       //     2,048
    float*         dinv   = (float*)(ws + 408576);     //   800,000
    int*           endArr = (int*)(ws + 1208576);      //   800,000
    int*           nlist  = (int*)(ws + 2008576);      //   800,000
    int*           E      = (int*)(ws + 2808576);      // 8,000,000
    int*           csr    = (int*)(ws + 10808576);     // 8,000,000
    float*         W12    = (float*)(ws + 18808576);   //    16,384
    float*         bb     = (float*)(ws + 18824960);   //       256
    ushortT*       embH   = (ushortT*)(ws + 18825216); // 25,600,000
    ushortT*       P1H    = (ushortT*)(ws + 44425216); // 25,600,000 (end ~70.0 MB)

    const int B = 256;

    // zero bCnt + ncnt + mark + need2 in one shot (region is contiguous)
    hipMemsetAsync(ws, 0, 404096, stream);

    k_prep     <<<12500, B, 0, stream>>>(emb, embH, edst, bCnt);
    k_mark     <<<(NBL + B - 1) / B, B, 0, stream>>>(inp, mark, need2);
    k_scanB_w12<<<10, 512, 0, stream>>>(bCnt, bStart, gCur, W1, W2, b1, W12, bb);
    k_bucket   <<<NCHUNK, B, 0, stream>>>(esrc, edst, gCur, E, mark, need2);
    k_csr      <<<NBKT, B, 0, stream>>>(E, bStart, need2, csr, dinv, endArr, nlist, ncnt);

    k_gather1  <<<2048, B, 0, stream>>>(nlist, ncnt, endArr, csr, dinv, embH, P1H);
    k_final    <<<(NBL + 3) / 4, B, 0, stream>>>(inp, endArr, csr, dinv, P1H, W12, bb, b2, out);
}

// Round 9
// 148.320 us; speedup vs baseline: 1.0505x; 1.0494x over previous
//
#include <hip/hip_runtime.h>

#define NTOKEN 200000
#define NINP   64
#define NEDGE  2000000
#define NBL    12800
#define NBKT   512
#define NPB    391            // nodes per bucket
#define CHUNK  2048
#define NCHUNK ((NEDGE + CHUNK - 1) / CHUNK)   // 977
#define CAPB   6144           // fixed per-bucket capacity (mean 3906, 35 sigma headroom)

typedef unsigned short ushortT;

#define B2F(h) __uint_as_float(((unsigned)(h)) << 16)
__device__ __forceinline__ ushortT f2b(float x) {
    unsigned u = __float_as_uint(x);
    return (ushortT)((u + 0x7FFFu + ((u >> 16) & 1u)) >> 16);   // RNE
}

// ---- inclusive scan of s[0..511] with 256 threads; p is 256-int temp ----
__device__ __forceinline__ void scan512(int* s, int* p) {
    int t = threadIdx.x;
    int a = s[2 * t], b = s[2 * t + 1];
    p[t] = a + b;
    __syncthreads();
    for (int d = 1; d < 256; d <<= 1) {
        int v = (t >= d) ? p[t - d] : 0;
        __syncthreads();
        p[t] += v;
        __syncthreads();
    }
    int incl = p[t];
    s[2 * t + 1] = incl;
    s[2 * t]     = incl - b;
    __syncthreads();
}

// ---- K1: emb fp32->bf16 convert (pure streaming) ----
__global__ void k_prep(const float* __restrict__ emb, ushortT* __restrict__ embH) {
    int id = blockIdx.x * blockDim.x + threadIdx.x;
    if (id < NTOKEN * NINP / 4) {
        float4 v = ((const float4*)emb)[id];
        ushort4 hh;
        hh.x = f2b(v.x); hh.y = f2b(v.y); hh.z = f2b(v.z); hh.w = f2b(v.w);
        ((ushort4*)embH)[id] = hh;
    }
}

// ---- K2: blocks 0..49 mark queried nodes; blocks 50..66 fold W12/bb ----
__global__ void k_mark_w12(const int* __restrict__ inp, unsigned char* __restrict__ mark,
                           unsigned char* __restrict__ need2,
                           const float* __restrict__ W1, const float* __restrict__ W2,
                           const float* __restrict__ b1, float* __restrict__ W12,
                           float* __restrict__ bb) {
    if (blockIdx.x < 50) {
        int t = blockIdx.x * 256 + threadIdx.x;
        if (t < NBL) { int n = inp[t]; mark[n] = 1; need2[n] = 1; }
    } else {
        int id = (blockIdx.x - 50) * 256 + threadIdx.x;
        if (id < 64 * 64) {
            int i = id >> 6, j = id & 63;
            float acc = 0.f;
            for (int k = 0; k < 128; ++k) acc += W1[i * 128 + k] * W2[k * 64 + j];
            W12[id] = acc;
        } else if (id < 64 * 64 + 64) {
            int j = id - 64 * 64;
            float acc = 0.f;
            for (int k = 0; k < 128; ++k) acc += b1[k] * W2[k * 64 + j];
            bb[j] = acc;
        }
    }
}

// ---- K3: chunked bucket scatter into fixed-capacity buckets + need2 marking ----
__global__ void k_bucket(const int* __restrict__ src, const int* __restrict__ dst,
                         int* __restrict__ gCur, int* __restrict__ E,
                         const unsigned char* __restrict__ mark,
                         unsigned char* __restrict__ need2) {
    __shared__ int sv[CHUNK];
    __shared__ int gd[CHUNK];
    __shared__ int h[NBKT];
    __shared__ int loff[NBKT];
    __shared__ int gb[NBKT];
    __shared__ int cur[NBKT];
    __shared__ int p[256];
    int t = threadIdx.x;
    int base = blockIdx.x * CHUNK;
    int cnt = NEDGE - base; if (cnt > CHUNK) cnt = CHUNK;

    h[t] = 0; h[t + 256] = 0; cur[t] = 0; cur[t + 256] = 0;
    __syncthreads();
    for (int j = t; j < cnt; j += 256)
        atomicAdd(&h[(unsigned)dst[base + j] / NPB], 1);
    __syncthreads();
    loff[2 * t] = h[2 * t]; loff[2 * t + 1] = h[2 * t + 1];
    __syncthreads();
    scan512(loff, p);
    if (h[t])       gb[t]       = atomicAdd(&gCur[t],       h[t]);
    if (h[t + 256]) gb[t + 256] = atomicAdd(&gCur[t + 256], h[t + 256]);
    loff[t]       -= h[t];
    loff[t + 256] -= h[t + 256];
    __syncthreads();
    for (int j = t; j < cnt; j += 256) {
        unsigned d = (unsigned)dst[base + j];
        unsigned b = d / NPB;
        int s = src[base + j];
        if (mark[d]) need2[s] = 1;          // layer-2 frontier expansion, fused
        int packed = (int)(((d - b * NPB) << 18) | (unsigned)s);
        int pl = atomicAdd(&cur[b], 1);
        int slot = loff[b] + pl;
        sv[slot] = packed;
        gd[slot] = (int)(b * CAPB) + gb[b] + pl;
    }
    __syncthreads();
    for (int j = t; j < cnt; j += 256)
        E[gd[j]] = sv[j];
}

// ---- K4: per-bucket CSR (selective placement, csr aliases E) + dinv + rows + nlist ----
__global__ void k_csr(const int* __restrict__ gCur, const unsigned char* __restrict__ need2,
                      int* __restrict__ E /* = csr, aliased */, float* __restrict__ dinv,
                      int2* __restrict__ rows, int* __restrict__ nlist,
                      int* __restrict__ ncnt) {
    __shared__ int eL[CAPB];
    __shared__ int csrL[CAPB];
    __shared__ int cnt[NBKT];
    __shared__ int off[NBKT];
    __shared__ int cur[NBKT];
    __shared__ int p[256];
    __shared__ unsigned char n2[NPB];
    __shared__ int nl[NPB];
    __shared__ int lcnt, nbase;
    int t = threadIdx.x;
    int b = blockIdx.x;
    int base = b * CAPB;
    int n = gCur[b];
    int nodes = NTOKEN - b * NPB; if (nodes > NPB) nodes = NPB;

    cnt[t] = 0; cnt[t + 256] = 0;
    if (t == 0) lcnt = 0;
    for (int i = t; i < nodes; i += 256) n2[i] = need2[b * NPB + i];
    __syncthreads();
    // stage bucket + per-node histogram
    for (int j = t; j < n; j += 256) {
        int v = E[base + j];
        eL[j] = v;
        atomicAdd(&cnt[v >> 18], 1);
    }
    __syncthreads();
    off[2 * t] = cnt[2 * t]; off[2 * t + 1] = cnt[2 * t + 1];
    __syncthreads();
    scan512(off, p);              // inclusive
    for (int i = t; i < nodes; i += 256) {
        int node = b * NPB + i;
        dinv[node] = rsqrtf((float)(cnt[i] + 1));
        rows[node] = make_int2(base + off[i] - cnt[i], base + off[i]);
        if (n2[i]) nl[atomicAdd(&lcnt, 1)] = node;
    }
    cur[t] = off[t] - cnt[t];
    cur[t + 256] = off[t + 256] - cnt[t + 256];
    __syncthreads();
    if (t == 0) nbase = lcnt ? atomicAdd(ncnt, lcnt) : 0;
    __syncthreads();
    for (int i = t; i < lcnt; i += 256) nlist[nbase + i] = nl[i];
    // in-LDS counting sort, needed rows only
    for (int j = t; j < n; j += 256) {
        int v = eL[j];
        int node = v >> 18;
        if (!n2[node]) continue;
        int pos = atomicAdd(&cur[node], 1);
        csrL[pos] = v & 0x3FFFF;
    }
    __syncthreads();
    for (int j = t; j < n; j += 256)
        E[base + j] = csrL[j];    // csr == E (staged in LDS, safe to overwrite)
}

// ---- per-node bf16 row gather; first edge batch passed in registers ----
__device__ __forceinline__ float node_gather(const ushortT* __restrict__ tab,
                                             const int* __restrict__ csr,
                                             const float* __restrict__ dinv,
                                             int b, int deg, int lane,
                                             int myE, float myW, float acc) {
    float a0 = acc, a1 = 0.f, a2 = 0.f, a3 = 0.f;
    int base = 0;
    while (true) {
        int m = deg - base; if (m > 64) m = 64;
        int e = 0;
        for (; e + 4 <= m; e += 4) {
            int   s0 = __shfl(myE, e),     s1 = __shfl(myE, e + 1);
            int   s2 = __shfl(myE, e + 2), s3 = __shfl(myE, e + 3);
            float w0 = __shfl(myW, e),     w1 = __shfl(myW, e + 1);
            float w2 = __shfl(myW, e + 2), w3 = __shfl(myW, e + 3);
            float v0 = B2F(tab[s0 * NINP + lane]);
            float v1 = B2F(tab[s1 * NINP + lane]);
            float v2 = B2F(tab[s2 * NINP + lane]);
            float v3 = B2F(tab[s3 * NINP + lane]);
            a0 += w0 * v0; a1 += w1 * v1; a2 += w2 * v2; a3 += w3 * v3;
        }
        for (; e < m; ++e) {
            int s0 = __shfl(myE, e); float w0 = __shfl(myW, e);
            a0 += w0 * B2F(tab[s0 * NINP + lane]);
        }
        base += 64;
        if (base >= deg) break;
        int mm = deg - base; if (mm > 64) mm = 64;
        myE = 0; myW = 0.f;
        if (lane < mm) { myE = csr[b + base + lane]; myW = dinv[myE]; }
    }
    return (a0 + a1) + (a2 + a3);
}

// ---- K5: layer-1 gather, two nodes per wave iteration ----
__global__ void k_gather1(const int* __restrict__ nlist, const int* __restrict__ ncnt,
                          const int2* __restrict__ rows, const int* __restrict__ csr,
                          const float* __restrict__ dinv, const ushortT* __restrict__ embH,
                          ushortT* __restrict__ P1H) {
    int lane = threadIdx.x & 63;
    int wid = blockIdx.x * (blockDim.x >> 6) + (threadIdx.x >> 6);
    int nw  = gridDim.x * (blockDim.x >> 6);
    int ncount = *ncnt;
    for (int p = wid; 2 * p < ncount; p += nw) {
        int i0 = nlist[2 * p];
        bool has1 = (2 * p + 1 < ncount);
        int i1 = has1 ? nlist[2 * p + 1] : i0;
        int2 r0 = rows[i0];
        int2 r1 = rows[i1];
        int b0 = r0.x, d0 = r0.y - r0.x;
        int b1 = r1.x, d1 = has1 ? (r1.y - r1.x) : 0;
        float di0 = dinv[i0];
        float di1 = dinv[i1];
        int m0 = d0 > 64 ? 64 : d0;
        int m1 = d1 > 64 ? 64 : d1;
        int e0 = 0; float w0 = 0.f;
        if (lane < m0) { e0 = csr[b0 + lane]; w0 = dinv[e0]; }
        int e1 = 0; float w1 = 0.f;
        if (lane < m1) { e1 = csr[b1 + lane]; w1 = dinv[e1]; }
        float self0 = di0 * B2F(embH[i0 * NINP + lane]);
        float self1 = di1 * B2F(embH[i1 * NINP + lane]);
        float r0v = node_gather(embH, csr, dinv, b0, d0, lane, e0, w0, self0);
        float r1v = node_gather(embH, csr, dinv, b1, d1, lane, e1, w1, self1);
        P1H[i0 * NINP + lane] = f2b(di0 * r0v);
        if (has1) P1H[i1 * NINP + lane] = f2b(di1 * r1v);
    }
}

// ---- K6: final layer-2 gather (8-way) + 64x64 GEMM + biases ----
__global__ void k_final(const int* __restrict__ inp, const int2* __restrict__ rows,
                        const int* __restrict__ csr, const float* __restrict__ dinv,
                        const ushortT* __restrict__ P1H, const float* __restrict__ W12,
                        const float* __restrict__ bb, const float* __restrict__ b2,
                        float* __restrict__ out) {
    int t = blockIdx.x * 4 + (threadIdx.x >> 6);
    if (t >= NBL) return;
    int lane = threadIdx.x & 63;
    int n = inp[t];
    float dn = dinv[n];
    int2 rn = rows[n];
    int b = rn.x;
    int deg = rn.y - rn.x;
    float a0 = dn * B2F(P1H[n * NINP + lane]);
    float a1 = 0.f, a2 = 0.f, a3 = 0.f, a4 = 0.f, a5 = 0.f, a6 = 0.f, a7 = 0.f;
    float sS = dn;
    for (int base = 0; base < deg; base += 64) {
        int m = deg - base; if (m > 64) m = 64;
        int myE = 0; float myW = 0.f;
        if (lane < m) { myE = csr[b + base + lane]; myW = dinv[myE]; }
        int e = 0;
        for (; e + 8 <= m; e += 8) {
            int   s0 = __shfl(myE, e),     s1 = __shfl(myE, e + 1);
            int   s2 = __shfl(myE, e + 2), s3 = __shfl(myE, e + 3);
            int   s4 = __shfl(myE, e + 4), s5 = __shfl(myE, e + 5);
            int   s6 = __shfl(myE, e + 6), s7 = __shfl(myE, e + 7);
            float w0 = __shfl(myW, e),     w1 = __shfl(myW, e + 1);
            float w2 = __shfl(myW, e + 2), w3 = __shfl(myW, e + 3);
            float w4 = __shfl(myW, e + 4), w5 = __shfl(myW, e + 5);
            float w6 = __shfl(myW, e + 6), w7 = __shfl(myW, e + 7);
            float v0 = B2F(P1H[s0 * NINP + lane]), v1 = B2F(P1H[s1 * NINP + lane]);
            float v2 = B2F(P1H[s2 * NINP + lane]), v3 = B2F(P1H[s3 * NINP + lane]);
            float v4 = B2F(P1H[s4 * NINP + lane]), v5 = B2F(P1H[s5 * NINP + lane]);
            float v6 = B2F(P1H[s6 * NINP + lane]), v7 = B2F(P1H[s7 * NINP + lane]);
            a0 += w0 * v0; a1 += w1 * v1; a2 += w2 * v2; a3 += w3 * v3;
            a4 += w4 * v4; a5 += w5 * v5; a6 += w6 * v6; a7 += w7 * v7;
            sS += ((w0 + w1) + (w2 + w3)) + ((w4 + w5) + (w6 + w7));
        }
        for (; e + 4 <= m; e += 4) {
            int   s0 = __shfl(myE, e),     s1 = __shfl(myE, e + 1);
            int   s2 = __shfl(myE, e + 2), s3 = __shfl(myE, e + 3);
            float w0 = __shfl(myW, e),     w1 = __shfl(myW, e + 1);
            float w2 = __shfl(myW, e + 2), w3 = __shfl(myW, e + 3);
            float v0 = B2F(P1H[s0 * NINP + lane]), v1 = B2F(P1H[s1 * NINP + lane]);
            float v2 = B2F(P1H[s2 * NINP + lane]), v3 = B2F(P1H[s3 * NINP + lane]);
            a0 += w0 * v0; a1 += w1 * v1; a2 += w2 * v2; a3 += w3 * v3;
            sS += (w0 + w1) + (w2 + w3);
        }
        for (; e < m; ++e) {
            int s0 = __shfl(myE, e); float w0 = __shfl(myW, e);
            a0 += w0 * B2F(P1H[s0 * NINP + lane]);
            sS += w0;
        }
    }
    float p2 = dn * ((((a0 + a1) + (a2 + a3)) + ((a4 + a5) + (a6 + a7))));
    float acc = b2[lane] + dn * sS * bb[lane];
#pragma unroll
    for (int k = 0; k < 64; ++k)
        acc += __shfl(p2, k) * W12[k * 64 + lane];
    out[t * 64 + lane] = acc;
}

extern "C" void kernel_launch(void* const* d_in, const int* in_sizes, int n_in,
                              void* d_out, int out_size, void* d_ws, size_t ws_size,
                              hipStream_t stream) {
    const int*   inp  = (const int*)d_in[0];
    const int*   eidx = (const int*)d_in[3];
    const int*   esrc = eidx;
    const int*   edst = eidx + NEDGE;
    const float* emb  = (const float*)d_in[4];
    const float* W1   = (const float*)d_in[5];
    const float* b1   = (const float*)d_in[6];
    const float* W2   = (const float*)d_in[7];
    const float* b2   = (const float*)d_in[8];
    float* out = (float*)d_out;

    char* ws = (char*)d_ws;
    int*           gCur   = (int*)(ws + 0);            //     2,048
    int*           ncnt   = (int*)(ws + 2048);         //         4
    unsigned char* mark   = (unsigned char*)(ws + 4096);      // 200,000
    unsigned char* need2  = (unsigned char*)(ws + 204096);    // 200,000
    int2*          rows   = (int2*)(ws + 404096);      // 1,600,000
    float*         dinv   = (float*)(ws + 2004096);    //   800,000
    int*           nlist  = (int*)(ws + 2804096);      //   800,000
    int*           E      = (int*)(ws + 3604096);      // 12,582,912 (csr aliases E)
    float*         W12    = (float*)(ws + 16187008);   //    16,384
    float*         bb     = (float*)(ws + 16203392);   //       256
    ushortT*       embH   = (ushortT*)(ws + 16203648); // 25,600,000
    ushortT*       P1H    = (ushortT*)(ws + 41803648); // 25,600,000 (end ~67.4 MB)

    const int B = 256;

    // zero gCur + ncnt + mark + need2 in one shot (contiguous region)
    hipMemsetAsync(ws, 0, 404096, stream);

    k_prep    <<<12500, B, 0, stream>>>(emb, embH);
    k_mark_w12<<<67, B, 0, stream>>>(inp, mark, need2, W1, W2, b1, W12, bb);
    k_bucket  <<<NCHUNK, B, 0, stream>>>(esrc, edst, gCur, E, mark, need2);
    k_csr     <<<NBKT, B, 0, stream>>>(gCur, need2, E, dinv, rows, nlist, ncnt);

    k_gather1 <<<2048, B, 0, stream>>>(nlist, ncnt, rows, E, dinv, embH, P1H);
    k_final   <<<(NBL + 3) / 4, B, 0, stream>>>(inp, rows, E, dinv, P1H, W12, bb, b2, out);
}

// Round 10
// 132.861 us; speedup vs baseline: 1.1727x; 1.1164x over previous
//
#include <hip/hip_runtime.h>

#define NTOKEN 200000
#define NINP   64
#define NEDGE  2000000
#define NBL    12800
#define NBKT   512
#define NPB    391            // nodes per bucket
#define CHUNK  4096
#define NCHK   ((NEDGE + CHUNK - 1) / CHUNK)   // 489
#define LROW   (NBKT + 1)                      // 513 ints per chunk in loffT
#define CAPB   6144           // per-bucket capacity (mean 3906, ~36 sigma headroom)

typedef unsigned short ushortT;

#define B2F(h) __uint_as_float(((unsigned)(h)) << 16)
__device__ __forceinline__ ushortT f2b(float x) {
    unsigned u = __float_as_uint(x);
    return (ushortT)((u + 0x7FFFu + ((u >> 16) & 1u)) >> 16);   // RNE
}

// ---- inclusive scan of s[0..511] with 256 threads; p is 256-int temp ----
__device__ __forceinline__ void scan512(int* s, int* p) {
    int t = threadIdx.x;
    int a = s[2 * t], b = s[2 * t + 1];
    p[t] = a + b;
    __syncthreads();
    for (int d = 1; d < 256; d <<= 1) {
        int v = (t >= d) ? p[t - d] : 0;
        __syncthreads();
        p[t] += v;
        __syncthreads();
    }
    int incl = p[t];
    s[2 * t + 1] = incl;
    s[2 * t]     = incl - b;
    __syncthreads();
}

// ---- K1: emb fp32->bf16 convert (pure streaming) ----
__global__ void k_prep(const float* __restrict__ emb, ushortT* __restrict__ embH) {
    int id = blockIdx.x * blockDim.x + threadIdx.x;
    if (id < NTOKEN * NINP / 4) {
        float4 v = ((const float4*)emb)[id];
        ushort4 hh;
        hh.x = f2b(v.x); hh.y = f2b(v.y); hh.z = f2b(v.z); hh.w = f2b(v.w);
        ((ushort4*)embH)[id] = hh;
    }
}

// ---- K2: blocks 0..49 mark queried nodes; blocks 50..66 fold W12/bb ----
__global__ void k_mark_w12(const int* __restrict__ inp, unsigned char* __restrict__ mark,
                           unsigned char* __restrict__ need2,
                           const float* __restrict__ W1, const float* __restrict__ W2,
                           const float* __restrict__ b1, float* __restrict__ W12,
                           float* __restrict__ bb) {
    if (blockIdx.x < 50) {
        int t = blockIdx.x * 256 + threadIdx.x;
        if (t < NBL) { int n = inp[t]; mark[n] = 1; need2[n] = 1; }
    } else {
        int id = (blockIdx.x - 50) * 256 + threadIdx.x;
        if (id < 64 * 64) {
            int i = id >> 6, j = id & 63;
            float acc = 0.f;
            for (int k = 0; k < 128; ++k) acc += W1[i * 128 + k] * W2[k * 64 + j];
            W12[id] = acc;
        } else if (id < 64 * 64 + 64) {
            int j = id - 64 * 64;
            float acc = 0.f;
            for (int k = 0; k < 128; ++k) acc += b1[k] * W2[k * 64 + j];
            bb[j] = acc;
        }
    }
}

// ---- K3: per-chunk LDS bucket sort, coalesced chunk-local writes, NO global atomics ----
__global__ void k_bucket(const int* __restrict__ src, const int* __restrict__ dst,
                         int* __restrict__ E, int* __restrict__ loffT,
                         const unsigned char* __restrict__ mark,
                         unsigned char* __restrict__ need2) {
    __shared__ int sv[CHUNK];
    __shared__ int h[NBKT];
    __shared__ int loff[NBKT];
    __shared__ int cur[NBKT];
    __shared__ int p[256];
    int t = threadIdx.x;
    int c = blockIdx.x;
    int base = c * CHUNK;
    int cnt = NEDGE - base; if (cnt > CHUNK) cnt = CHUNK;

    h[t] = 0; h[t + 256] = 0; cur[t] = 0; cur[t + 256] = 0;
    __syncthreads();
    for (int j = t; j < cnt; j += 256)
        atomicAdd(&h[(unsigned)dst[base + j] / NPB], 1);
    __syncthreads();
    loff[2 * t] = h[2 * t]; loff[2 * t + 1] = h[2 * t + 1];
    __syncthreads();
    scan512(loff, p);                       // inclusive
    int e0 = loff[t] - h[t];                // exclusive starts
    int e1 = loff[t + 256] - h[t + 256];
    loffT[c * LROW + t]       = e0;         // coalesced (chunk-major)
    loffT[c * LROW + t + 256] = e1;
    if (t == 0) loffT[c * LROW + 512] = cnt;
    loff[t] = e0; loff[t + 256] = e1;
    __syncthreads();
    for (int j = t; j < cnt; j += 256) {
        unsigned d = (unsigned)dst[base + j];
        unsigned b = d / NPB;
        int s = src[base + j];
        if (mark[d]) need2[s] = 1;          // layer-2 frontier expansion, fused
        int packed = (int)(((d - b * NPB) << 18) | (unsigned)s);
        int pl = atomicAdd(&cur[b], 1);
        sv[loff[b] + pl] = packed;
    }
    __syncthreads();
    for (int j = t; j < cnt; j += 256)
        E[base + j] = sv[j];                // fully coalesced, own chunk slot
}

// ---- K4: per-bucket segment-gather + CSR + dinv/rows/nlist ----
__global__ void k_csr(const int* __restrict__ E, const int* __restrict__ loffT,
                      const unsigned char* __restrict__ need2,
                      int* __restrict__ csr, float* __restrict__ dinv,
                      int2* __restrict__ rows, int* __restrict__ nlist,
                      int* __restrict__ ncnt) {
    __shared__ int eL[CAPB];
    __shared__ int csrL[CAPB];
    __shared__ int cnt[NBKT];
    __shared__ int off[NBKT];
    __shared__ int cur[NBKT];
    __shared__ int p[256];
    __shared__ int sgS[NBKT];     // per-chunk segment global start (0-padded >= NCHK)
    __shared__ int sgL[NBKT];     // per-chunk segment length
    __shared__ unsigned char n2[NPB];
    __shared__ int nl[NPB];
    __shared__ int lcnt, nbase;
    int t = threadIdx.x;
    int b = blockIdx.x;
    int nodes = NTOKEN - b * NPB; if (nodes > NPB) nodes = NPB;

    cnt[t] = 0; cnt[t + 256] = 0;
    if (t == 0) lcnt = 0;
    for (int i = t; i < nodes; i += 256) n2[i] = need2[b * NPB + i];
    for (int c = t; c < NBKT; c += 256) {
        int s = 0, l = 0;
        if (c < NCHK) {
            s = loffT[c * LROW + b];
            l = loffT[c * LROW + b + 1] - s;
            s += c * CHUNK;
        }
        sgS[c] = s; sgL[c] = l;
    }
    __syncthreads();
    off[2 * t] = sgL[2 * t]; off[2 * t + 1] = sgL[2 * t + 1];
    __syncthreads();
    scan512(off, p);                        // inclusive over segment lengths
    int n = off[NBKT - 1];                  // total edges in this bucket
    for (int c = t; c < NCHK; c += 256) {
        int o = off[c] - sgL[c];
        int s = sgS[c];
        int l = sgL[c];
        for (int k = 0; k < l; ++k)
            eL[o + k] = E[s + k];
    }
    __syncthreads();
    for (int j = t; j < n; j += 256)
        atomicAdd(&cnt[eL[j] >> 18], 1);
    __syncthreads();
    off[2 * t] = cnt[2 * t]; off[2 * t + 1] = cnt[2 * t + 1];
    __syncthreads();
    scan512(off, p);                        // inclusive per-node counts
    int cbase = b * CAPB;
    for (int i = t; i < nodes; i += 256) {
        int node = b * NPB + i;
        dinv[node] = rsqrtf((float)(cnt[i] + 1));
        rows[node] = make_int2(cbase + off[i] - cnt[i], cbase + off[i]);
        if (n2[i]) nl[atomicAdd(&lcnt, 1)] = node;
    }
    cur[t] = off[t] - cnt[t];
    cur[t + 256] = off[t + 256] - cnt[t + 256];
    __syncthreads();
    if (t == 0) nbase = lcnt ? atomicAdd(ncnt, lcnt) : 0;
    __syncthreads();
    for (int i = t; i < lcnt; i += 256) nlist[nbase + i] = nl[i];
    for (int j = t; j < n; j += 256) {      // selective placement: needed rows only
        int v = eL[j];
        int node = v >> 18;
        if (!n2[node]) continue;
        int pos = atomicAdd(&cur[node], 1);
        csrL[pos] = v & 0x3FFFF;
    }
    __syncthreads();
    for (int j = t; j < n; j += 256)
        csr[cbase + j] = csrL[j];
}

// ---- per-node bf16 row gather; first edge batch passed in registers ----
__device__ __forceinline__ float node_gather(const ushortT* __restrict__ tab,
                                             const int* __restrict__ csr,
                                             const float* __restrict__ dinv,
                                             int b, int deg, int lane,
                                             int myE, float myW, float acc) {
    float a0 = acc, a1 = 0.f, a2 = 0.f, a3 = 0.f;
    int base = 0;
    while (true) {
        int m = deg - base; if (m > 64) m = 64;
        int e = 0;
        for (; e + 4 <= m; e += 4) {
            int   s0 = __shfl(myE, e),     s1 = __shfl(myE, e + 1);
            int   s2 = __shfl(myE, e + 2), s3 = __shfl(myE, e + 3);
            float w0 = __shfl(myW, e),     w1 = __shfl(myW, e + 1);
            float w2 = __shfl(myW, e + 2), w3 = __shfl(myW, e + 3);
            float v0 = B2F(tab[s0 * NINP + lane]);
            float v1 = B2F(tab[s1 * NINP + lane]);
            float v2 = B2F(tab[s2 * NINP + lane]);
            float v3 = B2F(tab[s3 * NINP + lane]);
            a0 += w0 * v0; a1 += w1 * v1; a2 += w2 * v2; a3 += w3 * v3;
        }
        for (; e < m; ++e) {
            int s0 = __shfl(myE, e); float w0 = __shfl(myW, e);
            a0 += w0 * B2F(tab[s0 * NINP + lane]);
        }
        base += 64;
        if (base >= deg) break;
        int mm = deg - base; if (mm > 64) mm = 64;
        myE = 0; myW = 0.f;
        if (lane < mm) { myE = csr[b + base + lane]; myW = dinv[myE]; }
    }
    return (a0 + a1) + (a2 + a3);
}

// ---- K5: layer-1 gather, two nodes per wave iteration ----
__global__ void k_gather1(const int* __restrict__ nlist, const int* __restrict__ ncnt,
                          const int2* __restrict__ rows, const int* __restrict__ csr,
                          const float* __restrict__ dinv, const ushortT* __restrict__ embH,
                          ushortT* __restrict__ P1H) {
    int lane = threadIdx.x & 63;
    int wid = blockIdx.x * (blockDim.x >> 6) + (threadIdx.x >> 6);
    int nw  = gridDim.x * (blockDim.x >> 6);
    int ncount = *ncnt;
    for (int p = wid; 2 * p < ncount; p += nw) {
        int i0 = nlist[2 * p];
        bool has1 = (2 * p + 1 < ncount);
        int i1 = has1 ? nlist[2 * p + 1] : i0;
        int2 r0 = rows[i0];
        int2 r1 = rows[i1];
        int b0 = r0.x, d0 = r0.y - r0.x;
        int b1 = r1.x, d1 = has1 ? (r1.y - r1.x) : 0;
        float di0 = dinv[i0];
        float di1 = dinv[i1];
        int m0 = d0 > 64 ? 64 : d0;
        int m1 = d1 > 64 ? 64 : d1;
        int e0 = 0; float w0 = 0.f;
        if (lane < m0) { e0 = csr[b0 + lane]; w0 = dinv[e0]; }
        int e1 = 0; float w1 = 0.f;
        if (lane < m1) { e1 = csr[b1 + lane]; w1 = dinv[e1]; }
        float self0 = di0 * B2F(embH[i0 * NINP + lane]);
        float self1 = di1 * B2F(embH[i1 * NINP + lane]);
        float r0v = node_gather(embH, csr, dinv, b0, d0, lane, e0, w0, self0);
        float r1v = node_gather(embH, csr, dinv, b1, d1, lane, e1, w1, self1);
        P1H[i0 * NINP + lane] = f2b(di0 * r0v);
        if (has1) P1H[i1 * NINP + lane] = f2b(di1 * r1v);
    }
}

// ---- K6: final layer-2 gather (8-way) + 64x64 GEMM + biases ----
__global__ void k_final(const int* __restrict__ inp, const int2* __restrict__ rows,
                        const int* __restrict__ csr, const float* __restrict__ dinv,
                        const ushortT* __restrict__ P1H, const float* __restrict__ W12,
                        const float* __restrict__ bb, const float* __restrict__ b2,
                        float* __restrict__ out) {
    int t = blockIdx.x * 4 + (threadIdx.x >> 6);
    if (t >= NBL) return;
    int lane = threadIdx.x & 63;
    int n = inp[t];
    float dn = dinv[n];
    int2 rn = rows[n];
    int b = rn.x;
    int deg = rn.y - rn.x;
    float a0 = dn * B2F(P1H[n * NINP + lane]);
    float a1 = 0.f, a2 = 0.f, a3 = 0.f, a4 = 0.f, a5 = 0.f, a6 = 0.f, a7 = 0.f;
    float sS = dn;
    for (int base = 0; base < deg; base += 64) {
        int m = deg - base; if (m > 64) m = 64;
        int myE = 0; float myW = 0.f;
        if (lane < m) { myE = csr[b + base + lane]; myW = dinv[myE]; }
        int e = 0;
        for (; e + 8 <= m; e += 8) {
            int   s0 = __shfl(myE, e),     s1 = __shfl(myE, e + 1);
            int   s2 = __shfl(myE, e + 2), s3 = __shfl(myE, e + 3);
            int   s4 = __shfl(myE, e + 4), s5 = __shfl(myE, e + 5);
            int   s6 = __shfl(myE, e + 6), s7 = __shfl(myE, e + 7);
            float w0 = __shfl(myW, e),     w1 = __shfl(myW, e + 1);
            float w2 = __shfl(myW, e + 2), w3 = __shfl(myW, e + 3);
            float w4 = __shfl(myW, e + 4), w5 = __shfl(myW, e + 5);
            float w6 = __shfl(myW, e + 6), w7 = __shfl(myW, e + 7);
            float v0 = B2F(P1H[s0 * NINP + lane]), v1 = B2F(P1H[s1 * NINP + lane]);
            float v2 = B2F(P1H[s2 * NINP + lane]), v3 = B2F(P1H[s3 * NINP + lane]);
            float v4 = B2F(P1H[s4 * NINP + lane]), v5 = B2F(P1H[s5 * NINP + lane]);
            float v6 = B2F(P1H[s6 * NINP + lane]), v7 = B2F(P1H[s7 * NINP + lane]);
            a0 += w0 * v0; a1 += w1 * v1; a2 += w2 * v2; a3 += w3 * v3;
            a4 += w4 * v4; a5 += w5 * v5; a6 += w6 * v6; a7 += w7 * v7;
            sS += ((w0 + w1) + (w2 + w3)) + ((w4 + w5) + (w6 + w7));
        }
        for (; e + 4 <= m; e += 4) {
            int   s0 = __shfl(myE, e),     s1 = __shfl(myE, e + 1);
            int   s2 = __shfl(myE, e + 2), s3 = __shfl(myE, e + 3);
            float w0 = __shfl(myW, e),     w1 = __shfl(myW, e + 1);
            float w2 = __shfl(myW, e + 2), w3 = __shfl(myW, e + 3);
            float v0 = B2F(P1H[s0 * NINP + lane]), v1 = B2F(P1H[s1 * NINP + lane]);
            float v2 = B2F(P1H[s2 * NINP + lane]), v3 = B2F(P1H[s3 * NINP + lane]);
            a0 += w0 * v0; a1 += w1 * v1; a2 += w2 * v2; a3 += w3 * v3;
            sS += (w0 + w1) + (w2 + w3);
        }
        for (; e < m; ++e) {
            int s0 = __shfl(myE, e); float w0 = __shfl(myW, e);
            a0 += w0 * B2F(P1H[s0 * NINP + lane]);
            sS += w0;
        }
    }
    float p2 = dn * ((((a0 + a1) + (a2 + a3)) + ((a4 + a5) + (a6 + a7))));
    float acc = b2[lane] + dn * sS * bb[lane];
#pragma unroll
    for (int k = 0; k < 64; ++k)
        acc += __shfl(p2, k) * W12[k * 64 + lane];
    out[t * 64 + lane] = acc;
}

extern "C" void kernel_launch(void* const* d_in, const int* in_sizes, int n_in,
                              void* d_out, int out_size, void* d_ws, size_t ws_size,
                              hipStream_t stream) {
    const int*   inp  = (const int*)d_in[0];
    const int*   eidx = (const int*)d_in[3];
    const int*   esrc = eidx;
    const int*   edst = eidx + NEDGE;
    const float* emb  = (const float*)d_in[4];
    const float* W1   = (const float*)d_in[5];
    const float* b1   = (const float*)d_in[6];
    const float* W2   = (const float*)d_in[7];
    const float* b2   = (const float*)d_in[8];
    float* out = (float*)d_out;

    char* ws = (char*)d_ws;
    int*           ncnt   = (int*)(ws + 0);            //         4
    unsigned char* mark   = (unsigned char*)(ws + 4096);      // 200,000
    unsigned char* need2  = (unsigned char*)(ws + 204096);    // 200,000
    int2*          rows   = (int2*)(ws + 404096);      //  1,600,000
    float*         dinv   = (float*)(ws + 2004096);    //    800,000
    int*           nlist  = (int*)(ws + 2804096);      //    800,000
    int*           csr    = (int*)(ws + 3604096);      // 12,582,912
    float*         W12    = (float*)(ws + 16187008);   //     16,384
    float*         bb     = (float*)(ws + 16203392);   //        256
    ushortT*       embH   = (ushortT*)(ws + 16203648); // 25,600,000
    ushortT*       P1H    = (ushortT*)(ws + 41803648); // 25,600,000 (end 67,403,648)
    // E + loffT alias the P1H region: both dead before P1H is first written
    int*           E      = (int*)(ws + 41803648);     //  8,011,776
    int*           loffT  = (int*)(ws + 49815424);     //  1,003,428

    const int B = 256;

    // zero ncnt + mark + need2 in one shot (contiguous region)
    hipMemsetAsync(ws, 0, 404096, stream);

    k_prep    <<<12500, B, 0, stream>>>(emb, embH);
    k_mark_w12<<<67, B, 0, stream>>>(inp, mark, need2, W1, W2, b1, W12, bb);
    k_bucket  <<<NCHK, B, 0, stream>>>(esrc, edst, E, loffT, mark, need2);
    k_csr     <<<NBKT, B, 0, stream>>>(E, loffT, need2, csr, dinv, rows, nlist, ncnt);

    k_gather1 <<<2048, B, 0, stream>>>(nlist, ncnt, rows, csr, dinv, embH, P1H);
    k_final   <<<(NBL + 3) / 4, B, 0, stream>>>(inp, rows, csr, dinv, P1H, W12, bb, b2, out);
}

// Round 11
// 123.720 us; speedup vs baseline: 1.2594x; 1.0739x over previous
//
#include <hip/hip_runtime.h>

#define NTOKEN 200000
#define NINP   64
#define NEDGE  2000000
#define NBL    12800
#define NBKT   512
#define NPB    391            // nodes per bucket
#define CHUNK  4096
#define NCHK   ((NEDGE + CHUNK - 1) / CHUNK)   // 489
#define LROW   (NBKT + 1)                      // 513 ints per chunk in loffT
#define CAPB   6144           // per-bucket capacity (mean 3906, ~36 sigma headroom)

typedef unsigned short ushortT;

#define B2F(h) __uint_as_float(((unsigned)(h)) << 16)
__device__ __forceinline__ ushortT f2b(float x) {
    unsigned u = __float_as_uint(x);
    return (ushortT)((u + 0x7FFFu + ((u >> 16) & 1u)) >> 16);   // RNE
}

// ---- inclusive scan of s[0..511] with 256 threads; p is 256-int temp ----
__device__ __forceinline__ void scan512(int* s, int* p) {
    int t = threadIdx.x;
    int a = s[2 * t], b = s[2 * t + 1];
    p[t] = a + b;
    __syncthreads();
    for (int d = 1; d < 256; d <<= 1) {
        int v = (t >= d) ? p[t - d] : 0;
        __syncthreads();
        p[t] += v;
        __syncthreads();
    }
    int incl = p[t];
    s[2 * t + 1] = incl;
    s[2 * t]     = incl - b;
    __syncthreads();
}

// ---- K1: fused emb->bf16 convert (blocks 0..12499) + mark (12500..12549) + W12 fold ----
__global__ void k_prep(const float* __restrict__ emb, ushortT* __restrict__ embH,
                       const int* __restrict__ inp, unsigned char* __restrict__ mark,
                       unsigned char* __restrict__ need2,
                       const float* __restrict__ W1, const float* __restrict__ W2,
                       const float* __restrict__ b1, float* __restrict__ W12,
                       float* __restrict__ bb) {
    int blk = blockIdx.x;
    if (blk < 12500) {
        int id = blk * 256 + threadIdx.x;       // 12500*256 == NTOKEN*NINP/4 exactly
        float4 v = ((const float4*)emb)[id];
        ushort4 hh;
        hh.x = f2b(v.x); hh.y = f2b(v.y); hh.z = f2b(v.z); hh.w = f2b(v.w);
        ((ushort4*)embH)[id] = hh;
    } else if (blk < 12550) {
        int t2 = (blk - 12500) * 256 + threadIdx.x;
        if (t2 < NBL) { int n = inp[t2]; mark[n] = 1; need2[n] = 1; }
    } else {
        int id = (blk - 12550) * 256 + threadIdx.x;
        if (id < 64 * 64) {
            int i = id >> 6, j = id & 63;
            float acc = 0.f;
            for (int k = 0; k < 128; ++k) acc += W1[i * 128 + k] * W2[k * 64 + j];
            W12[id] = acc;
        } else if (id < 64 * 64 + 64) {
            int j = id - 64 * 64;
            float acc = 0.f;
            for (int k = 0; k < 128; ++k) acc += b1[k] * W2[k * 64 + j];
            bb[j] = acc;
        }
    }
}

// ---- K2: per-chunk LDS bucket sort, coalesced chunk-local writes, NO global atomics ----
__global__ void k_bucket(const int* __restrict__ src, const int* __restrict__ dst,
                         int* __restrict__ E, int* __restrict__ loffT,
                         const unsigned char* __restrict__ mark,
                         unsigned char* __restrict__ need2) {
    __shared__ int sv[CHUNK];
    __shared__ int h[NBKT];
    __shared__ int loff[NBKT];
    __shared__ int cur[NBKT];
    __shared__ int p[256];
    int t = threadIdx.x;
    int c = blockIdx.x;
    int base = c * CHUNK;
    int cnt = NEDGE - base; if (cnt > CHUNK) cnt = CHUNK;

    h[t] = 0; h[t + 256] = 0; cur[t] = 0; cur[t + 256] = 0;
    __syncthreads();
    for (int j = t; j < cnt; j += 256)
        atomicAdd(&h[(unsigned)dst[base + j] / NPB], 1);
    __syncthreads();
    loff[2 * t] = h[2 * t]; loff[2 * t + 1] = h[2 * t + 1];
    __syncthreads();
    scan512(loff, p);                       // inclusive
    int e0 = loff[t] - h[t];                // exclusive starts
    int e1 = loff[t + 256] - h[t + 256];
    loffT[c * LROW + t]       = e0;         // coalesced (chunk-major)
    loffT[c * LROW + t + 256] = e1;
    if (t == 0) loffT[c * LROW + 512] = cnt;
    loff[t] = e0; loff[t + 256] = e1;
    __syncthreads();
    for (int j = t; j < cnt; j += 256) {
        unsigned d = (unsigned)dst[base + j];
        unsigned b = d / NPB;
        int s = src[base + j];
        if (mark[d]) need2[s] = 1;          // layer-2 frontier expansion, fused
        int packed = (int)(((d - b * NPB) << 18) | (unsigned)s);
        int pl = atomicAdd(&cur[b], 1);
        sv[loff[b] + pl] = packed;
    }
    __syncthreads();
    for (int j = t; j < cnt; j += 256)
        E[base + j] = sv[j];                // fully coalesced, own chunk slot
}

// ---- K3: per-bucket segment-gather + CSR + dinv/rows/nlist ----
__global__ void k_csr(const int* __restrict__ E, const int* __restrict__ loffT,
                      const unsigned char* __restrict__ need2,
                      int* __restrict__ csr, float* __restrict__ dinv,
                      int2* __restrict__ rows, int* __restrict__ nlist,
                      int* __restrict__ ncnt) {
    __shared__ int eL[CAPB];
    __shared__ int csrL[CAPB];
    __shared__ int cnt[NBKT];
    __shared__ int off[NBKT];
    __shared__ int cur[NBKT];
    __shared__ int p[256];
    __shared__ int sgS[NBKT];
    __shared__ int sgL[NBKT];
    __shared__ unsigned char n2[NPB];
    __shared__ int nl[NPB];
    __shared__ int lcnt, nbase;
    int t = threadIdx.x;
    int b = blockIdx.x;
    int nodes = NTOKEN - b * NPB; if (nodes > NPB) nodes = NPB;

    cnt[t] = 0; cnt[t + 256] = 0;
    if (t == 0) lcnt = 0;
    for (int i = t; i < nodes; i += 256) n2[i] = need2[b * NPB + i];
    for (int c = t; c < NBKT; c += 256) {
        int s = 0, l = 0;
        if (c < NCHK) {
            s = loffT[c * LROW + b];
            l = loffT[c * LROW + b + 1] - s;
            s += c * CHUNK;
        }
        sgS[c] = s; sgL[c] = l;
    }
    __syncthreads();
    off[2 * t] = sgL[2 * t]; off[2 * t + 1] = sgL[2 * t + 1];
    __syncthreads();
    scan512(off, p);                        // inclusive over segment lengths
    int n = off[NBKT - 1];
    for (int c = t; c < NCHK; c += 256) {
        int o = off[c] - sgL[c];
        int s = sgS[c];
        int l = sgL[c];
        for (int k = 0; k < l; ++k)
            eL[o + k] = E[s + k];
    }
    __syncthreads();
    for (int j = t; j < n; j += 256)
        atomicAdd(&cnt[eL[j] >> 18], 1);
    __syncthreads();
    off[2 * t] = cnt[2 * t]; off[2 * t + 1] = cnt[2 * t + 1];
    __syncthreads();
    scan512(off, p);
    int cbase = b * CAPB;
    for (int i = t; i < nodes; i += 256) {
        int node = b * NPB + i;
        dinv[node] = rsqrtf((float)(cnt[i] + 1));
        rows[node] = make_int2(cbase + off[i] - cnt[i], cbase + off[i]);
        if (n2[i]) nl[atomicAdd(&lcnt, 1)] = node;
    }
    cur[t] = off[t] - cnt[t];
    cur[t + 256] = off[t + 256] - cnt[t + 256];
    __syncthreads();
    if (t == 0) nbase = lcnt ? atomicAdd(ncnt, lcnt) : 0;
    __syncthreads();
    for (int i = t; i < lcnt; i += 256) nlist[nbase + i] = nl[i];
    for (int j = t; j < n; j += 256) {
        int v = eL[j];
        int node = v >> 18;
        if (!n2[node]) continue;
        int pos = atomicAdd(&cur[node], 1);
        csrL[pos] = v & 0x3FFFF;
    }
    __syncthreads();
    for (int j = t; j < n; j += 256)
        csr[cbase + j] = csrL[j];
}

// ---- quad-row gather: 4 edges per load instruction; returns per-qf float4 sums,
//      edge-weight sum in *sw. Lanes: qf=lane&15 (feature quad), qe=lane>>4 (edge slot).
__device__ __forceinline__ float4 quad_gather(const ushortT* __restrict__ tab,
                                              const int* __restrict__ csr,
                                              const float* __restrict__ dinv,
                                              int b, int deg, int lane, int qe, int qf,
                                              int myE, float myW, float* sw) {
    float ax0 = 0.f, ay0 = 0.f, az0 = 0.f, aw0 = 0.f;
    float ax1 = 0.f, ay1 = 0.f, az1 = 0.f, aw1 = 0.f;
    float ws = 0.f;
    int base = 0;
    while (base < deg) {
        int m = deg - base; if (m > 64) m = 64;
        for (int e = 0; e < m; e += 8) {
            int   sA = __shfl(myE, e + qe);
            float wA = __shfl(myW, e + qe);
            int   sB = __shfl(myE, e + 4 + qe);
            float wB = __shfl(myW, e + 4 + qe);
            uint2 vA = *(const uint2*)(tab + sA * NINP + qf * 4);
            uint2 vB = *(const uint2*)(tab + sB * NINP + qf * 4);
            ax0 += wA * __uint_as_float(vA.x << 16);
            ay0 += wA * __uint_as_float(vA.x & 0xffff0000u);
            az0 += wA * __uint_as_float(vA.y << 16);
            aw0 += wA * __uint_as_float(vA.y & 0xffff0000u);
            ax1 += wB * __uint_as_float(vB.x << 16);
            ay1 += wB * __uint_as_float(vB.x & 0xffff0000u);
            az1 += wB * __uint_as_float(vB.y << 16);
            aw1 += wB * __uint_as_float(vB.y & 0xffff0000u);
            ws  += wA + wB;
        }
        base += 64;
        if (base >= deg) break;
        int mm = deg - base; if (mm > 64) mm = 64;
        myE = 0; myW = 0.f;
        if (lane < mm) { myE = csr[b + base + lane]; myW = dinv[myE]; }
    }
    float4 r;
    r.x = ax0 + ax1; r.y = ay0 + ay1; r.z = az0 + az1; r.w = aw0 + aw1;
    r.x += __shfl_xor(r.x, 16); r.y += __shfl_xor(r.y, 16);
    r.z += __shfl_xor(r.z, 16); r.w += __shfl_xor(r.w, 16);
    r.x += __shfl_xor(r.x, 32); r.y += __shfl_xor(r.y, 32);
    r.z += __shfl_xor(r.z, 32); r.w += __shfl_xor(r.w, 32);
    ws += __shfl_xor(ws, 16); ws += __shfl_xor(ws, 32);
    *sw = ws;
    return r;
}

// ---- K4: layer-1 gather, two nodes per wave iteration, quad-row loads ----
__global__ void k_gather1(const int* __restrict__ nlist, const int* __restrict__ ncnt,
                          const int2* __restrict__ rows, const int* __restrict__ csr,
                          const float* __restrict__ dinv, const ushortT* __restrict__ embH,
                          ushortT* __restrict__ P1H) {
    int lane = threadIdx.x & 63;
    int qe = lane >> 4, qf = lane & 15;
    int wid = blockIdx.x * (blockDim.x >> 6) + (threadIdx.x >> 6);
    int nw  = gridDim.x * (blockDim.x >> 6);
    int ncount = *ncnt;
    for (int p = wid; 2 * p < ncount; p += nw) {
        int i0 = nlist[2 * p];
        bool has1 = (2 * p + 1 < ncount);
        int i1 = has1 ? nlist[2 * p + 1] : i0;
        int2 r0 = rows[i0];
        int2 r1 = rows[i1];
        int b0 = r0.x, d0 = r0.y - r0.x;
        int b1 = r1.x, d1 = has1 ? (r1.y - r1.x) : 0;
        float di0 = dinv[i0];
        float di1 = dinv[i1];
        int m0 = d0 > 64 ? 64 : d0;
        int m1 = d1 > 64 ? 64 : d1;
        int e0 = 0; float w0 = 0.f;
        if (lane < m0) { e0 = csr[b0 + lane]; w0 = dinv[e0]; }
        int e1 = 0; float w1 = 0.f;
        if (lane < m1) { e1 = csr[b1 + lane]; w1 = dinv[e1]; }
        float sw0, sw1;
        float4 g0 = quad_gather(embH, csr, dinv, b0, d0, lane, qe, qf, e0, w0, &sw0);
        float4 g1 = quad_gather(embH, csr, dinv, b1, d1, lane, qe, qf, e1, w1, &sw1);
        if (qe == 0) {
            uint2 sv0 = *(const uint2*)(embH + i0 * NINP + qf * 4);
            ushort4 o0;
            o0.x = f2b(di0 * (di0 * __uint_as_float(sv0.x << 16)         + g0.x));
            o0.y = f2b(di0 * (di0 * __uint_as_float(sv0.x & 0xffff0000u) + g0.y));
            o0.z = f2b(di0 * (di0 * __uint_as_float(sv0.y << 16)         + g0.z));
            o0.w = f2b(di0 * (di0 * __uint_as_float(sv0.y & 0xffff0000u) + g0.w));
            *(ushort4*)(P1H + i0 * NINP + qf * 4) = o0;
            if (has1) {
                uint2 sv1 = *(const uint2*)(embH + i1 * NINP + qf * 4);
                ushort4 o1;
                o1.x = f2b(di1 * (di1 * __uint_as_float(sv1.x << 16)         + g1.x));
                o1.y = f2b(di1 * (di1 * __uint_as_float(sv1.x & 0xffff0000u) + g1.y));
                o1.z = f2b(di1 * (di1 * __uint_as_float(sv1.y << 16)         + g1.z));
                o1.w = f2b(di1 * (di1 * __uint_as_float(sv1.y & 0xffff0000u) + g1.w));
                *(ushort4*)(P1H + i1 * NINP + qf * 4) = o1;
            }
        }
    }
}

// ---- K5: final layer-2 quad gather + 64x64 GEMM + biases ----
__global__ void k_final(const int* __restrict__ inp, const int2* __restrict__ rows,
                        const int* __restrict__ csr, const float* __restrict__ dinv,
                        const ushortT* __restrict__ P1H, const float* __restrict__ W12,
                        const float* __restrict__ bb, const float* __restrict__ b2,
                        float* __restrict__ out) {
    int t = blockIdx.x * 4 + (threadIdx.x >> 6);
    if (t >= NBL) return;
    int lane = threadIdx.x & 63;
    int qe = lane >> 4, qf = lane & 15;
    int n = inp[t];
    float dn = dinv[n];
    int2 rn = rows[n];
    int b = rn.x;
    int deg = rn.y - rn.x;
    int m = deg > 64 ? 64 : deg;
    int myE = 0; float myW = 0.f;
    if (lane < m) { myE = csr[b + lane]; myW = dinv[myE]; }
    float sw;
    float4 g = quad_gather(P1H, csr, dinv, b, deg, lane, qe, qf, myE, myW, &sw);
    uint2 sv = *(const uint2*)(P1H + n * NINP + qf * 4);
    float4 p2;
    p2.x = dn * (dn * __uint_as_float(sv.x << 16)         + g.x);
    p2.y = dn * (dn * __uint_as_float(sv.x & 0xffff0000u) + g.y);
    p2.z = dn * (dn * __uint_as_float(sv.y << 16)         + g.z);
    p2.w = dn * (dn * __uint_as_float(sv.y & 0xffff0000u) + g.w);
    float sS = dn + sw;
    float acc = b2[lane] + dn * sS * bb[lane];
#pragma unroll
    for (int q = 0; q < 16; ++q) {
        float px = __shfl(p2.x, q), py = __shfl(p2.y, q);
        float pz = __shfl(p2.z, q), pw = __shfl(p2.w, q);
        acc += px * W12[(4 * q + 0) * 64 + lane] + py * W12[(4 * q + 1) * 64 + lane]
             + pz * W12[(4 * q + 2) * 64 + lane] + pw * W12[(4 * q + 3) * 64 + lane];
    }
    out[t * 64 + lane] = acc;
}

extern "C" void kernel_launch(void* const* d_in, const int* in_sizes, int n_in,
                              void* d_out, int out_size, void* d_ws, size_t ws_size,
                              hipStream_t stream) {
    const int*   inp  = (const int*)d_in[0];
    const int*   eidx = (const int*)d_in[3];
    const int*   esrc = eidx;
    const int*   edst = eidx + NEDGE;
    const float* emb  = (const float*)d_in[4];
    const float* W1   = (const float*)d_in[5];
    const float* b1   = (const float*)d_in[6];
    const float* W2   = (const float*)d_in[7];
    const float* b2   = (const float*)d_in[8];
    float* out = (float*)d_out;

    char* ws = (char*)d_ws;
    int*           ncnt   = (int*)(ws + 0);            //         4
    unsigned char* mark   = (unsigned char*)(ws + 4096);      // 200,000
    unsigned char* need2  = (unsigned char*)(ws + 204096);    // 200,000
    int2*          rows   = (int2*)(ws + 404096);      //  1,600,000
    float*         dinv   = (float*)(ws + 2004096);    //    800,000
    int*           nlist  = (int*)(ws + 2804096);      //    800,000
    int*           csr    = (int*)(ws + 3604096);      // 12,582,912
    float*         W12    = (float*)(ws + 16187008);   //     16,384
    float*         bb     = (float*)(ws + 16203392);   //        256
    ushortT*       embH   = (ushortT*)(ws + 16203648); // 25,600,000
    ushortT*       P1H    = (ushortT*)(ws + 41803648); // 25,600,000 (end 67,403,648)
    // E + loffT alias the P1H region: both dead before P1H is first written
    int*           E      = (int*)(ws + 41803648);     //  8,011,776
    int*           loffT  = (int*)(ws + 49815424);     //  1,003,428

    const int B = 256;

    // zero ncnt + mark + need2 in one shot (contiguous region)
    hipMemsetAsync(ws, 0, 404096, stream);

    k_prep   <<<12567, B, 0, stream>>>(emb, embH, inp, mark, need2, W1, W2, b1, W12, bb);
    k_bucket <<<NCHK, B, 0, stream>>>(esrc, edst, E, loffT, mark, need2);
    k_csr    <<<NBKT, B, 0, stream>>>(E, loffT, need2, csr, dinv, rows, nlist, ncnt);

    k_gather1<<<2048, B, 0, stream>>>(nlist, ncnt, rows, csr, dinv, embH, P1H);
    k_final  <<<(NBL + 3) / 4, B, 0, stream>>>(inp, rows, csr, dinv, P1H, W12, bb, b2, out);
}

// Round 12
// 122.189 us; speedup vs baseline: 1.2751x; 1.0125x over previous
//
#include <hip/hip_runtime.h>

#define NTOKEN 200000
#define NINP   64
#define NEDGE  2000000
#define NBL    12800
#define NBKT   512
#define NPB    391            // nodes per bucket
#define CHUNK  4096
#define NCHK   ((NEDGE + CHUNK - 1) / CHUNK)   // 489
#define LROW   (NBKT + 1)                      // 513 ints per chunk in loffT
#define CAPB   6144           // per-bucket capacity (mean 3906, ~36 sigma headroom)

typedef unsigned short ushortT;

#define B2F(h) __uint_as_float(((unsigned)(h)) << 16)
__device__ __forceinline__ ushortT f2b(float x) {
    unsigned u = __float_as_uint(x);
    return (ushortT)((u + 0x7FFFu + ((u >> 16) & 1u)) >> 16);   // RNE
}

// ---- inclusive scan of s[0..511] with 256 threads; p is 256-int temp ----
__device__ __forceinline__ void scan512(int* s, int* p) {
    int t = threadIdx.x;
    int a = s[2 * t], b = s[2 * t + 1];
    p[t] = a + b;
    __syncthreads();
    for (int d = 1; d < 256; d <<= 1) {
        int v = (t >= d) ? p[t - d] : 0;
        __syncthreads();
        p[t] += v;
        __syncthreads();
    }
    int incl = p[t];
    s[2 * t + 1] = incl;
    s[2 * t]     = incl - b;
    __syncthreads();
}

// ---- K0: zero ncnt+mark+need2 (404,096 B as ints) — replaces 40us runtime fill ----
__global__ void k_zero(int* __restrict__ z) {
    int i = blockIdx.x * blockDim.x + threadIdx.x;
    if (i < 404096 / 4) z[i] = 0;
}

// ---- K1: fused emb->bf16 convert (blocks 0..12499) + mark (12500..12549) + W12 fold ----
__global__ void k_prep(const float* __restrict__ emb, ushortT* __restrict__ embH,
                       const int* __restrict__ inp, unsigned char* __restrict__ mark,
                       unsigned char* __restrict__ need2,
                       const float* __restrict__ W1, const float* __restrict__ W2,
                       const float* __restrict__ b1, float* __restrict__ W12,
                       float* __restrict__ bb) {
    int blk = blockIdx.x;
    if (blk < 12500) {
        int id = blk * 256 + threadIdx.x;       // 12500*256 == NTOKEN*NINP/4 exactly
        float4 v = ((const float4*)emb)[id];
        ushort4 hh;
        hh.x = f2b(v.x); hh.y = f2b(v.y); hh.z = f2b(v.z); hh.w = f2b(v.w);
        ((ushort4*)embH)[id] = hh;
    } else if (blk < 12550) {
        int t2 = (blk - 12500) * 256 + threadIdx.x;
        if (t2 < NBL) { int n = inp[t2]; mark[n] = 1; need2[n] = 1; }
    } else {
        int id = (blk - 12550) * 256 + threadIdx.x;
        if (id < 64 * 64) {
            int i = id >> 6, j = id & 63;
            float acc = 0.f;
            for (int k = 0; k < 128; ++k) acc += W1[i * 128 + k] * W2[k * 64 + j];
            W12[id] = acc;
        } else if (id < 64 * 64 + 64) {
            int j = id - 64 * 64;
            float acc = 0.f;
            for (int k = 0; k < 128; ++k) acc += b1[k] * W2[k * 64 + j];
            bb[j] = acc;
        }
    }
}

// ---- K2: per-chunk LDS bucket sort, coalesced chunk-local writes, NO global atomics ----
__global__ void k_bucket(const int* __restrict__ src, const int* __restrict__ dst,
                         int* __restrict__ E, int* __restrict__ loffT,
                         const unsigned char* __restrict__ mark,
                         unsigned char* __restrict__ need2) {
    __shared__ int sv[CHUNK];
    __shared__ int h[NBKT];
    __shared__ int loff[NBKT];
    __shared__ int cur[NBKT];
    __shared__ int p[256];
    int t = threadIdx.x;
    int c = blockIdx.x;
    int base = c * CHUNK;
    int cnt = NEDGE - base; if (cnt > CHUNK) cnt = CHUNK;

    h[t] = 0; h[t + 256] = 0; cur[t] = 0; cur[t + 256] = 0;
    __syncthreads();
    for (int j = t; j < cnt; j += 256)
        atomicAdd(&h[(unsigned)dst[base + j] / NPB], 1);
    __syncthreads();
    loff[2 * t] = h[2 * t]; loff[2 * t + 1] = h[2 * t + 1];
    __syncthreads();
    scan512(loff, p);                       // inclusive
    int e0 = loff[t] - h[t];                // exclusive starts
    int e1 = loff[t + 256] - h[t + 256];
    loffT[c * LROW + t]       = e0;         // coalesced (chunk-major)
    loffT[c * LROW + t + 256] = e1;
    if (t == 0) loffT[c * LROW + 512] = cnt;
    loff[t] = e0; loff[t + 256] = e1;
    __syncthreads();
    for (int j = t; j < cnt; j += 256) {
        unsigned d = (unsigned)dst[base + j];
        unsigned b = d / NPB;
        int s = src[base + j];
        if (mark[d]) need2[s] = 1;          // layer-2 frontier expansion, fused
        int packed = (int)(((d - b * NPB) << 18) | (unsigned)s);
        int pl = atomicAdd(&cur[b], 1);
        sv[loff[b] + pl] = packed;
    }
    __syncthreads();
    for (int j = t; j < cnt; j += 256)
        E[base + j] = sv[j];                // fully coalesced, own chunk slot
}

// ---- K3: per-bucket segment-gather + CSR + dinv/rows/nlist ----
__global__ void k_csr(const int* __restrict__ E, const int* __restrict__ loffT,
                      const unsigned char* __restrict__ need2,
                      int* __restrict__ csr, float* __restrict__ dinv,
                      int2* __restrict__ rows, int* __restrict__ nlist,
                      int* __restrict__ ncnt) {
    __shared__ int eL[CAPB];
    __shared__ int csrL[CAPB];
    __shared__ int cnt[NBKT];
    __shared__ int off[NBKT];
    __shared__ int cur[NBKT];
    __shared__ int p[256];
    __shared__ int sgS[NBKT];
    __shared__ int sgL[NBKT];
    __shared__ unsigned char n2[NPB];
    __shared__ int nl[NPB];
    __shared__ int lcnt, nbase;
    int t = threadIdx.x;
    int b = blockIdx.x;
    int nodes = NTOKEN - b * NPB; if (nodes > NPB) nodes = NPB;

    cnt[t] = 0; cnt[t + 256] = 0;
    if (t == 0) lcnt = 0;
    for (int i = t; i < nodes; i += 256) n2[i] = need2[b * NPB + i];
    for (int c = t; c < NBKT; c += 256) {
        int s = 0, l = 0;
        if (c < NCHK) {
            s = loffT[c * LROW + b];
            l = loffT[c * LROW + b + 1] - s;
            s += c * CHUNK;
        }
        sgS[c] = s; sgL[c] = l;
    }
    __syncthreads();
    off[2 * t] = sgL[2 * t]; off[2 * t + 1] = sgL[2 * t + 1];
    __syncthreads();
    scan512(off, p);                        // inclusive over segment lengths
    int n = off[NBKT - 1];
    for (int c = t; c < NCHK; c += 256) {
        int o = off[c] - sgL[c];
        int s = sgS[c];
        int l = sgL[c];
        for (int k = 0; k < l; ++k)
            eL[o + k] = E[s + k];
    }
    __syncthreads();
    for (int j = t; j < n; j += 256)
        atomicAdd(&cnt[eL[j] >> 18], 1);
    __syncthreads();
    off[2 * t] = cnt[2 * t]; off[2 * t + 1] = cnt[2 * t + 1];
    __syncthreads();
    scan512(off, p);
    int cbase = b * CAPB;
    for (int i = t; i < nodes; i += 256) {
        int node = b * NPB + i;
        dinv[node] = rsqrtf((float)(cnt[i] + 1));
        rows[node] = make_int2(cbase + off[i] - cnt[i], cbase + off[i]);
        if (n2[i]) nl[atomicAdd(&lcnt, 1)] = node;
    }
    cur[t] = off[t] - cnt[t];
    cur[t + 256] = off[t + 256] - cnt[t + 256];
    __syncthreads();
    if (t == 0) nbase = lcnt ? atomicAdd(ncnt, lcnt) : 0;
    __syncthreads();
    for (int i = t; i < lcnt; i += 256) nlist[nbase + i] = nl[i];
    for (int j = t; j < n; j += 256) {
        int v = eL[j];
        int node = v >> 18;
        if (!n2[node]) continue;
        int pos = atomicAdd(&cur[node], 1);
        csrL[pos] = v & 0x3FFFF;
    }
    __syncthreads();
    for (int j = t; j < n; j += 256)
        csr[cbase + j] = csrL[j];
}

// ---- quad-row gather: 4 edges per load instruction; returns per-qf float4 sums,
//      edge-weight sum in *sw. Lanes: qf=lane&15 (feature quad), qe=lane>>4 (edge slot).
__device__ __forceinline__ float4 quad_gather(const ushortT* __restrict__ tab,
                                              const int* __restrict__ csr,
                                              const float* __restrict__ dinv,
                                              int b, int deg, int lane, int qe, int qf,
                                              int myE, float myW, float* sw) {
    float ax0 = 0.f, ay0 = 0.f, az0 = 0.f, aw0 = 0.f;
    float ax1 = 0.f, ay1 = 0.f, az1 = 0.f, aw1 = 0.f;
    float ws = 0.f;
    int base = 0;
    while (base < deg) {
        int m = deg - base; if (m > 64) m = 64;
        for (int e = 0; e < m; e += 8) {
            int   sA = __shfl(myE, e + qe);
            float wA = __shfl(myW, e + qe);
            int   sB = __shfl(myE, e + 4 + qe);
            float wB = __shfl(myW, e + 4 + qe);
            uint2 vA = *(const uint2*)(tab + sA * NINP + qf * 4);
            uint2 vB = *(const uint2*)(tab + sB * NINP + qf * 4);
            ax0 += wA * __uint_as_float(vA.x << 16);
            ay0 += wA * __uint_as_float(vA.x & 0xffff0000u);
            az0 += wA * __uint_as_float(vA.y << 16);
            aw0 += wA * __uint_as_float(vA.y & 0xffff0000u);
            ax1 += wB * __uint_as_float(vB.x << 16);
            ay1 += wB * __uint_as_float(vB.x & 0xffff0000u);
            az1 += wB * __uint_as_float(vB.y << 16);
            aw1 += wB * __uint_as_float(vB.y & 0xffff0000u);
            ws  += wA + wB;
        }
        base += 64;
        if (base >= deg) break;
        int mm = deg - base; if (mm > 64) mm = 64;
        myE = 0; myW = 0.f;
        if (lane < mm) { myE = csr[b + base + lane]; myW = dinv[myE]; }
    }
    float4 r;
    r.x = ax0 + ax1; r.y = ay0 + ay1; r.z = az0 + az1; r.w = aw0 + aw1;
    r.x += __shfl_xor(r.x, 16); r.y += __shfl_xor(r.y, 16);
    r.z += __shfl_xor(r.z, 16); r.w += __shfl_xor(r.w, 16);
    r.x += __shfl_xor(r.x, 32); r.y += __shfl_xor(r.y, 32);
    r.z += __shfl_xor(r.z, 32); r.w += __shfl_xor(r.w, 32);
    ws += __shfl_xor(ws, 16); ws += __shfl_xor(ws, 32);
    *sw = ws;
    return r;
}

// ---- K4: layer-1 gather, two nodes per wave iteration, quad-row loads ----
__global__ void k_gather1(const int* __restrict__ nlist, const int* __restrict__ ncnt,
                          const int2* __restrict__ rows, const int* __restrict__ csr,
                          const float* __restrict__ dinv, const ushortT* __restrict__ embH,
                          ushortT* __restrict__ P1H) {
    int lane = threadIdx.x & 63;
    int qe = lane >> 4, qf = lane & 15;
    int wid = blockIdx.x * (blockDim.x >> 6) + (threadIdx.x >> 6);
    int nw  = gridDim.x * (blockDim.x >> 6);
    int ncount = *ncnt;
    for (int p = wid; 2 * p < ncount; p += nw) {
        int i0 = nlist[2 * p];
        bool has1 = (2 * p + 1 < ncount);
        int i1 = has1 ? nlist[2 * p + 1] : i0;
        int2 r0 = rows[i0];
        int2 r1 = rows[i1];
        int b0 = r0.x, d0 = r0.y - r0.x;
        int b1 = r1.x, d1 = has1 ? (r1.y - r1.x) : 0;
        float di0 = dinv[i0];
        float di1 = dinv[i1];
        int m0 = d0 > 64 ? 64 : d0;
        int m1 = d1 > 64 ? 64 : d1;
        int e0 = 0; float w0 = 0.f;
        if (lane < m0) { e0 = csr[b0 + lane]; w0 = dinv[e0]; }
        int e1 = 0; float w1 = 0.f;
        if (lane < m1) { e1 = csr[b1 + lane]; w1 = dinv[e1]; }
        float sw0, sw1;
        float4 g0 = quad_gather(embH, csr, dinv, b0, d0, lane, qe, qf, e0, w0, &sw0);
        float4 g1 = quad_gather(embH, csr, dinv, b1, d1, lane, qe, qf, e1, w1, &sw1);
        if (qe == 0) {
            uint2 sv0 = *(const uint2*)(embH + i0 * NINP + qf * 4);
            ushort4 o0;
            o0.x = f2b(di0 * (di0 * __uint_as_float(sv0.x << 16)         + g0.x));
            o0.y = f2b(di0 * (di0 * __uint_as_float(sv0.x & 0xffff0000u) + g0.y));
            o0.z = f2b(di0 * (di0 * __uint_as_float(sv0.y << 16)         + g0.z));
            o0.w = f2b(di0 * (di0 * __uint_as_float(sv0.y & 0xffff0000u) + g0.w));
            *(ushort4*)(P1H + i0 * NINP + qf * 4) = o0;
            if (has1) {
                uint2 sv1 = *(const uint2*)(embH + i1 * NINP + qf * 4);
                ushort4 o1;
                o1.x = f2b(di1 * (di1 * __uint_as_float(sv1.x << 16)         + g1.x));
                o1.y = f2b(di1 * (di1 * __uint_as_float(sv1.x & 0xffff0000u) + g1.y));
                o1.z = f2b(di1 * (di1 * __uint_as_float(sv1.y << 16)         + g1.z));
                o1.w = f2b(di1 * (di1 * __uint_as_float(sv1.y & 0xffff0000u) + g1.w));
                *(ushort4*)(P1H + i1 * NINP + qf * 4) = o1;
            }
        }
    }
}

// ---- K5: final layer-2 quad gather + 64x64 GEMM + biases ----
__global__ void k_final(const int* __restrict__ inp, const int2* __restrict__ rows,
                        const int* __restrict__ csr, const float* __restrict__ dinv,
                        const ushortT* __restrict__ P1H, const float* __restrict__ W12,
                        const float* __restrict__ bb, const float* __restrict__ b2,
                        float* __restrict__ out) {
    int t = blockIdx.x * 4 + (threadIdx.x >> 6);
    if (t >= NBL) return;
    int lane = threadIdx.x & 63;
    int qe = lane >> 4, qf = lane & 15;
    int n = inp[t];
    float dn = dinv[n];
    int2 rn = rows[n];
    int b = rn.x;
    int deg = rn.y - rn.x;
    int m = deg > 64 ? 64 : deg;
    int myE = 0; float myW = 0.f;
    if (lane < m) { myE = csr[b + lane]; myW = dinv[myE]; }
    float sw;
    float4 g = quad_gather(P1H, csr, dinv, b, deg, lane, qe, qf, myE, myW, &sw);
    uint2 sv = *(const uint2*)(P1H + n * NINP + qf * 4);
    float4 p2;
    p2.x = dn * (dn * __uint_as_float(sv.x << 16)         + g.x);
    p2.y = dn * (dn * __uint_as_float(sv.x & 0xffff0000u) + g.y);
    p2.z = dn * (dn * __uint_as_float(sv.y << 16)         + g.z);
    p2.w = dn * (dn * __uint_as_float(sv.y & 0xffff0000u) + g.w);
    float sS = dn + sw;
    float acc = b2[lane] + dn * sS * bb[lane];
#pragma unroll
    for (int q = 0; q < 16; ++q) {
        float px = __shfl(p2.x, q), py = __shfl(p2.y, q);
        float pz = __shfl(p2.z, q), pw = __shfl(p2.w, q);
        acc += px * W12[(4 * q + 0) * 64 + lane] + py * W12[(4 * q + 1) * 64 + lane]
             + pz * W12[(4 * q + 2) * 64 + lane] + pw * W12[(4 * q + 3) * 64 + lane];
    }
    out[t * 64 + lane] = acc;
}

extern "C" void kernel_launch(void* const* d_in, const int* in_sizes, int n_in,
                              void* d_out, int out_size, void* d_ws, size_t ws_size,
                              hipStream_t stream) {
    const int*   inp  = (const int*)d_in[0];
    const int*   eidx = (const int*)d_in[3];
    const int*   esrc = eidx;
    const int*   edst = eidx + NEDGE;
    const float* emb  = (const float*)d_in[4];
    const float* W1   = (const float*)d_in[5];
    const float* b1   = (const float*)d_in[6];
    const float* W2   = (const float*)d_in[7];
    const float* b2   = (const float*)d_in[8];
    float* out = (float*)d_out;

    char* ws = (char*)d_ws;
    int*           ncnt   = (int*)(ws + 0);            //         4
    unsigned char* mark   = (unsigned char*)(ws + 4096);      // 200,000
    unsigned char* need2  = (unsigned char*)(ws + 204096);    // 200,000
    int2*          rows   = (int2*)(ws + 404096);      //  1,600,000
    float*         dinv   = (float*)(ws + 2004096);    //    800,000
    int*           nlist  = (int*)(ws + 2804096);      //    800,000
    int*           csr    = (int*)(ws + 3604096);      // 12,582,912
    float*         W12    = (float*)(ws + 16187008);   //     16,384
    float*         bb     = (float*)(ws + 16203392);   //        256
    ushortT*       embH   = (ushortT*)(ws + 16203648); // 25,600,000
    ushortT*       P1H    = (ushortT*)(ws + 41803648); // 25,600,000 (end 67,403,648)
    // E + loffT alias the P1H region: both dead before P1H is first written
    int*           E      = (int*)(ws + 41803648);     //  8,011,776
    int*           loffT  = (int*)(ws + 49815424);     //  1,003,428

    const int B = 256;

    k_zero   <<<(404096 / 4 + B - 1) / B, B, 0, stream>>>((int*)ws);
    k_prep   <<<12567, B, 0, stream>>>(emb, embH, inp, mark, need2, W1, W2, b1, W12, bb);
    k_bucket <<<NCHK, B, 0, stream>>>(esrc, edst, E, loffT, mark, need2);
    k_csr    <<<NBKT, B, 0, stream>>>(E, loffT, need2, csr, dinv, rows, nlist, ncnt);

    k_gather1<<<2048, B, 0, stream>>>(nlist, ncnt, rows, csr, dinv, embH, P1H);
    k_final  <<<(NBL + 3) / 4, B, 0, stream>>>(inp, rows, csr, dinv, P1H, W12, bb, b2, out);
}

// Round 13
// 119.889 us; speedup vs baseline: 1.2996x; 1.0192x over previous
//
#include <hip/hip_runtime.h>

#define NTOKEN 200000
#define NINP   64
#define NEDGE  2000000
#define NBL    12800
#define NBKT   512
#define NPB    391            // nodes per bucket
#define CHUNK  4096
#define NCHK   ((NEDGE + CHUNK - 1) / CHUNK)   // 489
#define LROW   (NBKT + 1)                      // 513 ints per chunk in loffT
#define CAPB   6144           // per-bucket capacity (mean 3906, ~36 sigma headroom)
#define NCONV  12500          // emb-convert blocks (12500*256*4 == NTOKEN*NINP)

typedef unsigned short ushortT;

#define B2F(h) __uint_as_float(((unsigned)(h)) << 16)
__device__ __forceinline__ ushortT f2b(float x) {
    unsigned u = __float_as_uint(x);
    return (ushortT)((u + 0x7FFFu + ((u >> 16) & 1u)) >> 16);   // RNE
}

// ---- inclusive scan of s[0..511] with 256 threads; p is 256-int temp ----
__device__ __forceinline__ void scan512(int* s, int* p) {
    int t = threadIdx.x;
    int a = s[2 * t], b = s[2 * t + 1];
    p[t] = a + b;
    __syncthreads();
    for (int d = 1; d < 256; d <<= 1) {
        int v = (t >= d) ? p[t - d] : 0;
        __syncthreads();
        p[t] += v;
        __syncthreads();
    }
    int incl = p[t];
    s[2 * t + 1] = incl;
    s[2 * t]     = incl - b;
    __syncthreads();
}

// ---- K0: zero ncnt+mark+need2 (404,096 B as ints) ----
__global__ void k_zero(int* __restrict__ z) {
    int i = blockIdx.x * blockDim.x + threadIdx.x;
    if (i < 404096 / 4) z[i] = 0;
}

// ---- K1: blocks 0..49 mark queried nodes; blocks 50..66 fold W12/bb ----
__global__ void k_mark_w12(const int* __restrict__ inp, unsigned char* __restrict__ mark,
                           unsigned char* __restrict__ need2,
                           const float* __restrict__ W1, const float* __restrict__ W2,
                           const float* __restrict__ b1, float* __restrict__ W12,
                           float* __restrict__ bb) {
    if (blockIdx.x < 50) {
        int t = blockIdx.x * 256 + threadIdx.x;
        if (t < NBL) { int n = inp[t]; mark[n] = 1; need2[n] = 1; }
    } else {
        int id = (blockIdx.x - 50) * 256 + threadIdx.x;
        if (id < 64 * 64) {
            int i = id >> 6, j = id & 63;
            float acc = 0.f;
            for (int k = 0; k < 128; ++k) acc += W1[i * 128 + k] * W2[k * 64 + j];
            W12[id] = acc;
        } else if (id < 64 * 64 + 64) {
            int j = id - 64 * 64;
            float acc = 0.f;
            for (int k = 0; k < 128; ++k) acc += b1[k] * W2[k * 64 + j];
            bb[j] = acc;
        }
    }
}

// ---- K2: blocks 0..NCHK-1: per-chunk LDS bucket sort (no global atomics);
//          blocks NCHK..NCHK+NCONV-1: emb fp32->bf16 streaming convert (overlapped) ----
__global__ void k_bucket(const int* __restrict__ src, const int* __restrict__ dst,
                         int* __restrict__ E, int* __restrict__ loffT,
                         const unsigned char* __restrict__ mark,
                         unsigned char* __restrict__ need2,
                         const float* __restrict__ emb, ushortT* __restrict__ embH) {
    __shared__ int sv[CHUNK];
    __shared__ int h[NBKT];
    __shared__ int loff[NBKT];
    __shared__ int cur[NBKT];
    __shared__ int p[256];
    int t = threadIdx.x;
    int c = blockIdx.x;
    if (c >= NCHK) {                        // convert block: pure streaming, no LDS
        int id = (c - NCHK) * 256 + t;      // NCONV*256 == NTOKEN*NINP/4 exactly
        float4 v = ((const float4*)emb)[id];
        ushort4 hh;
        hh.x = f2b(v.x); hh.y = f2b(v.y); hh.z = f2b(v.z); hh.w = f2b(v.w);
        ((ushort4*)embH)[id] = hh;
        return;
    }
    int base = c * CHUNK;
    int cnt = NEDGE - base; if (cnt > CHUNK) cnt = CHUNK;

    h[t] = 0; h[t + 256] = 0; cur[t] = 0; cur[t + 256] = 0;
    __syncthreads();
    for (int j = t; j < cnt; j += 256)
        atomicAdd(&h[(unsigned)dst[base + j] / NPB], 1);
    __syncthreads();
    loff[2 * t] = h[2 * t]; loff[2 * t + 1] = h[2 * t + 1];
    __syncthreads();
    scan512(loff, p);                       // inclusive
    int e0 = loff[t] - h[t];                // exclusive starts
    int e1 = loff[t + 256] - h[t + 256];
    loffT[c * LROW + t]       = e0;         // coalesced (chunk-major)
    loffT[c * LROW + t + 256] = e1;
    if (t == 0) loffT[c * LROW + 512] = cnt;
    loff[t] = e0; loff[t + 256] = e1;
    __syncthreads();
    for (int j = t; j < cnt; j += 256) {
        unsigned d = (unsigned)dst[base + j];
        unsigned b = d / NPB;
        int s = src[base + j];
        if (mark[d]) need2[s] = 1;          // layer-2 frontier expansion, fused
        int packed = (int)(((d - b * NPB) << 18) | (unsigned)s);
        int pl = atomicAdd(&cur[b], 1);
        sv[loff[b] + pl] = packed;
    }
    __syncthreads();
    for (int j = t; j < cnt; j += 256)
        E[base + j] = sv[j];                // fully coalesced, own chunk slot
}

// ---- K3: per-bucket segment-gather + CSR + dinv/rows/nlist ----
__global__ void k_csr(const int* __restrict__ E, const int* __restrict__ loffT,
                      const unsigned char* __restrict__ need2,
                      int* __restrict__ csr, float* __restrict__ dinv,
                      int2* __restrict__ rows, int* __restrict__ nlist,
                      int* __restrict__ ncnt) {
    __shared__ int eL[CAPB];
    __shared__ int csrL[CAPB];
    __shared__ int cnt[NBKT];
    __shared__ int off[NBKT];
    __shared__ int cur[NBKT];
    __shared__ int p[256];
    __shared__ int sgS[NBKT];
    __shared__ int sgL[NBKT];
    __shared__ unsigned char n2[NPB];
    __shared__ int nl[NPB];
    __shared__ int lcnt, nbase;
    int t = threadIdx.x;
    int b = blockIdx.x;
    int nodes = NTOKEN - b * NPB; if (nodes > NPB) nodes = NPB;

    cnt[t] = 0; cnt[t + 256] = 0;
    if (t == 0) lcnt = 0;
    for (int i = t; i < nodes; i += 256) n2[i] = need2[b * NPB + i];
    for (int c = t; c < NBKT; c += 256) {
        int s = 0, l = 0;
        if (c < NCHK) {
            s = loffT[c * LROW + b];
            l = loffT[c * LROW + b + 1] - s;
            s += c * CHUNK;
        }
        sgS[c] = s; sgL[c] = l;
    }
    __syncthreads();
    off[2 * t] = sgL[2 * t]; off[2 * t + 1] = sgL[2 * t + 1];
    __syncthreads();
    scan512(off, p);                        // inclusive over segment lengths
    int n = off[NBKT - 1];
    for (int c = t; c < NCHK; c += 256) {
        int o = off[c] - sgL[c];
        int s = sgS[c];
        int l = sgL[c];
        for (int k = 0; k < l; ++k)
            eL[o + k] = E[s + k];
    }
    __syncthreads();
    for (int j = t; j < n; j += 256)
        atomicAdd(&cnt[eL[j] >> 18], 1);
    __syncthreads();
    off[2 * t] = cnt[2 * t]; off[2 * t + 1] = cnt[2 * t + 1];
    __syncthreads();
    scan512(off, p);
    int cbase = b * CAPB;
    for (int i = t; i < nodes; i += 256) {
        int node = b * NPB + i;
        dinv[node] = rsqrtf((float)(cnt[i] + 1));
        rows[node] = make_int2(cbase + off[i] - cnt[i], cbase + off[i]);
        if (n2[i]) nl[atomicAdd(&lcnt, 1)] = node;
    }
    cur[t] = off[t] - cnt[t];
    cur[t + 256] = off[t + 256] - cnt[t + 256];
    __syncthreads();
    if (t == 0) nbase = lcnt ? atomicAdd(ncnt, lcnt) : 0;
    __syncthreads();
    for (int i = t; i < lcnt; i += 256) nlist[nbase + i] = nl[i];
    for (int j = t; j < n; j += 256) {
        int v = eL[j];
        int node = v >> 18;
        if (!n2[node]) continue;
        int pos = atomicAdd(&cur[node], 1);
        csrL[pos] = v & 0x3FFFF;
    }
    __syncthreads();
    for (int j = t; j < n; j += 256)
        csr[cbase + j] = csrL[j];
}

// ---- quad-row gather: 4 edges per load instruction; returns per-qf float4 sums,
//      edge-weight sum in *sw. Lanes: qf=lane&15 (feature quad), qe=lane>>4 (edge slot).
__device__ __forceinline__ float4 quad_gather(const ushortT* __restrict__ tab,
                                              const int* __restrict__ csr,
                                              const float* __restrict__ dinv,
                                              int b, int deg, int lane, int qe, int qf,
                                              int myE, float myW, float* sw) {
    float ax0 = 0.f, ay0 = 0.f, az0 = 0.f, aw0 = 0.f;
    float ax1 = 0.f, ay1 = 0.f, az1 = 0.f, aw1 = 0.f;
    float ws = 0.f;
    int base = 0;
    while (base < deg) {
        int m = deg - base; if (m > 64) m = 64;
        for (int e = 0; e < m; e += 8) {
            int   sA = __shfl(myE, e + qe);
            float wA = __shfl(myW, e + qe);
            int   sB = __shfl(myE, e + 4 + qe);
            float wB = __shfl(myW, e + 4 + qe);
            uint2 vA = *(const uint2*)(tab + sA * NINP + qf * 4);
            uint2 vB = *(const uint2*)(tab + sB * NINP + qf * 4);
            ax0 += wA * __uint_as_float(vA.x << 16);
            ay0 += wA * __uint_as_float(vA.x & 0xffff0000u);
            az0 += wA * __uint_as_float(vA.y << 16);
            aw0 += wA * __uint_as_float(vA.y & 0xffff0000u);
            ax1 += wB * __uint_as_float(vB.x << 16);
            ay1 += wB * __uint_as_float(vB.x & 0xffff0000u);
            az1 += wB * __uint_as_float(vB.y << 16);
            aw1 += wB * __uint_as_float(vB.y & 0xffff0000u);
            ws  += wA + wB;
        }
        base += 64;
        if (base >= deg) break;
        int mm = deg - base; if (mm > 64) mm = 64;
        myE = 0; myW = 0.f;
        if (lane < mm) { myE = csr[b + base + lane]; myW = dinv[myE]; }
    }
    float4 r;
    r.x = ax0 + ax1; r.y = ay0 + ay1; r.z = az0 + az1; r.w = aw0 + aw1;
    r.x += __shfl_xor(r.x, 16); r.y += __shfl_xor(r.y, 16);
    r.z += __shfl_xor(r.z, 16); r.w += __shfl_xor(r.w, 16);
    r.x += __shfl_xor(r.x, 32); r.y += __shfl_xor(r.y, 32);
    r.z += __shfl_xor(r.z, 32); r.w += __shfl_xor(r.w, 32);
    ws += __shfl_xor(ws, 16); ws += __shfl_xor(ws, 32);
    *sw = ws;
    return r;
}

// ---- K4: layer-1 gather, two nodes per wave iteration, quad-row loads ----
__global__ void k_gather1(const int* __restrict__ nlist, const int* __restrict__ ncnt,
                          const int2* __restrict__ rows, const int* __restrict__ csr,
                          const float* __restrict__ dinv, const ushortT* __restrict__ embH,
                          ushortT* __restrict__ P1H) {
    int lane = threadIdx.x & 63;
    int qe = lane >> 4, qf = lane & 15;
    int wid = blockIdx.x * (blockDim.x >> 6) + (threadIdx.x >> 6);
    int nw  = gridDim.x * (blockDim.x >> 6);
    int ncount = *ncnt;
    for (int p = wid; 2 * p < ncount; p += nw) {
        int i0 = nlist[2 * p];
        bool has1 = (2 * p + 1 < ncount);
        int i1 = has1 ? nlist[2 * p + 1] : i0;
        int2 r0 = rows[i0];
        int2 r1 = rows[i1];
        int b0 = r0.x, d0 = r0.y - r0.x;
        int b1 = r1.x, d1 = has1 ? (r1.y - r1.x) : 0;
        float di0 = dinv[i0];
        float di1 = dinv[i1];
        int m0 = d0 > 64 ? 64 : d0;
        int m1 = d1 > 64 ? 64 : d1;
        int e0 = 0; float w0 = 0.f;
        if (lane < m0) { e0 = csr[b0 + lane]; w0 = dinv[e0]; }
        int e1 = 0; float w1 = 0.f;
        if (lane < m1) { e1 = csr[b1 + lane]; w1 = dinv[e1]; }
        float sw0, sw1;
        float4 g0 = quad_gather(embH, csr, dinv, b0, d0, lane, qe, qf, e0, w0, &sw0);
        float4 g1 = quad_gather(embH, csr, dinv, b1, d1, lane, qe, qf, e1, w1, &sw1);
        if (qe == 0) {
            uint2 sv0 = *(const uint2*)(embH + i0 * NINP + qf * 4);
            ushort4 o0;
            o0.x = f2b(di0 * (di0 * __uint_as_float(sv0.x << 16)         + g0.x));
            o0.y = f2b(di0 * (di0 * __uint_as_float(sv0.x & 0xffff0000u) + g0.y));
            o0.z = f2b(di0 * (di0 * __uint_as_float(sv0.y << 16)         + g0.z));
            o0.w = f2b(di0 * (di0 * __uint_as_float(sv0.y & 0xffff0000u) + g0.w));
            *(ushort4*)(P1H + i0 * NINP + qf * 4) = o0;
            if (has1) {
                uint2 sv1 = *(const uint2*)(embH + i1 * NINP + qf * 4);
                ushort4 o1;
                o1.x = f2b(di1 * (di1 * __uint_as_float(sv1.x << 16)         + g1.x));
                o1.y = f2b(di1 * (di1 * __uint_as_float(sv1.x & 0xffff0000u) + g1.y));
                o1.z = f2b(di1 * (di1 * __uint_as_float(sv1.y << 16)         + g1.z));
                o1.w = f2b(di1 * (di1 * __uint_as_float(sv1.y & 0xffff0000u) + g1.w));
                *(ushort4*)(P1H + i1 * NINP + qf * 4) = o1;
            }
        }
    }
}

// ---- K5: final layer-2 quad gather + 64x64 GEMM + biases ----
__global__ void k_final(const int* __restrict__ inp, const int2* __restrict__ rows,
                        const int* __restrict__ csr, const float* __restrict__ dinv,
                        const ushortT* __restrict__ P1H, const float* __restrict__ W12,
                        const float* __restrict__ bb, const float* __restrict__ b2,
                        float* __restrict__ out) {
    int t = blockIdx.x * 4 + (threadIdx.x >> 6);
    if (t >= NBL) return;
    int lane = threadIdx.x & 63;
    int qe = lane >> 4, qf = lane & 15;
    int n = inp[t];
    float dn = dinv[n];
    int2 rn = rows[n];
    int b = rn.x;
    int deg = rn.y - rn.x;
    int m = deg > 64 ? 64 : deg;
    int myE = 0; float myW = 0.f;
    if (lane < m) { myE = csr[b + lane]; myW = dinv[myE]; }
    float sw;
    float4 g = quad_gather(P1H, csr, dinv, b, deg, lane, qe, qf, myE, myW, &sw);
    uint2 sv = *(const uint2*)(P1H + n * NINP + qf * 4);
    float4 p2;
    p2.x = dn * (dn * __uint_as_float(sv.x << 16)         + g.x);
    p2.y = dn * (dn * __uint_as_float(sv.x & 0xffff0000u) + g.y);
    p2.z = dn * (dn * __uint_as_float(sv.y << 16)         + g.z);
    p2.w = dn * (dn * __uint_as_float(sv.y & 0xffff0000u) + g.w);
    float sS = dn + sw;
    float acc = b2[lane] + dn * sS * bb[lane];
#pragma unroll
    for (int q = 0; q < 16; ++q) {
        float px = __shfl(p2.x, q), py = __shfl(p2.y, q);
        float pz = __shfl(p2.z, q), pw = __shfl(p2.w, q);
        acc += px * W12[(4 * q + 0) * 64 + lane] + py * W12[(4 * q + 1) * 64 + lane]
             + pz * W12[(4 * q + 2) * 64 + lane] + pw * W12[(4 * q + 3) * 64 + lane];
    }
    out[t * 64 + lane] = acc;
}

extern "C" void kernel_launch(void* const* d_in, const int* in_sizes, int n_in,
                              void* d_out, int out_size, void* d_ws, size_t ws_size,
                              hipStream_t stream) {
    const int*   inp  = (const int*)d_in[0];
    const int*   eidx = (const int*)d_in[3];
    const int*   esrc = eidx;
    const int*   edst = eidx + NEDGE;
    const float* emb  = (const float*)d_in[4];
    const float* W1   = (const float*)d_in[5];
    const float* b1   = (const float*)d_in[6];
    const float* W2   = (const float*)d_in[7];
    const float* b2   = (const float*)d_in[8];
    float* out = (float*)d_out;

    char* ws = (char*)d_ws;
    int*           ncnt   = (int*)(ws + 0);            //         4
    unsigned char* mark   = (unsigned char*)(ws + 4096);      // 200,000
    unsigned char* need2  = (unsigned char*)(ws + 204096);    // 200,000
    int2*          rows   = (int2*)(ws + 404096);      //  1,600,000
    float*         dinv   = (float*)(ws + 2004096);    //    800,000
    int*           nlist  = (int*)(ws + 2804096);      //    800,000
    int*           csr    = (int*)(ws + 3604096);      // 12,582,912
    float*         W12    = (float*)(ws + 16187008);   //     16,384
    float*         bb     = (float*)(ws + 16203392);   //        256
    ushortT*       embH   = (ushortT*)(ws + 16203648); // 25,600,000
    ushortT*       P1H    = (ushortT*)(ws + 41803648); // 25,600,000 (end 67,403,648)
    // E + loffT alias the P1H region: both dead before P1H is first written
    int*           E      = (int*)(ws + 41803648);     //  8,011,776
    int*           loffT  = (int*)(ws + 49815424);     //  1,003,428

    const int B = 256;

    k_zero    <<<(404096 / 4 + B - 1) / B, B, 0, stream>>>((int*)ws);
    k_mark_w12<<<67, B, 0, stream>>>(inp, mark, need2, W1, W2, b1, W12, bb);
    k_bucket  <<<NCHK + NCONV, B, 0, stream>>>(esrc, edst, E, loffT, mark, need2, emb, embH);
    k_csr     <<<NBKT, B, 0, stream>>>(E, loffT, need2, csr, dinv, rows, nlist, ncnt);

    k_gather1 <<<2048, B, 0, stream>>>(nlist, ncnt, rows, csr, dinv, embH, P1H);
    k_final   <<<(NBL + 3) / 4, B, 0, stream>>>(inp, rows, csr, dinv, P1H, W12, bb, b2, out);
}

// Round 14
// 109.963 us; speedup vs baseline: 1.4169x; 1.0903x over previous
//
#include <hip/hip_runtime.h>

#define NTOKEN 200000
#define NINP   64
#define NEDGE  2000000
#define NBL    12800
#define NBKT   512
#define NPB    391            // nodes per bucket
#define CHUNK  4096
#define NCHK   ((NEDGE + CHUNK - 1) / CHUNK)   // 489
#define LROW   (NBKT + 1)                      // 513 ints per chunk in loffT
#define CAPB   6144           // per-bucket capacity (mean 3906, ~36 sigma headroom)
#define NCONV  6250           // emb-convert blocks at 512 thr (6250*512*4 == NTOKEN*NINP)

typedef unsigned short ushortT;

#define B2F(h) __uint_as_float(((unsigned)(h)) << 16)
__device__ __forceinline__ ushortT f2b(float x) {
    unsigned u = __float_as_uint(x);
    return (ushortT)((u + 0x7FFFu + ((u >> 16) & 1u)) >> 16);   // RNE
}

// ---- inclusive scan over s[0..511], 512 threads, caller syncs before ----
__device__ __forceinline__ void scan512b(int* s) {
    int t = threadIdx.x;
    for (int d = 1; d < 512; d <<= 1) {
        int v = (t >= d) ? s[t - d] : 0;
        __syncthreads();
        s[t] += v;
        __syncthreads();
    }
}

// ---- K0: zero ncnt+mark+need2 (404,096 B as ints) ----
__global__ void k_zero(int* __restrict__ z) {
    int i = blockIdx.x * blockDim.x + threadIdx.x;
    if (i < 404096 / 4) z[i] = 0;
}

// ---- K1: blocks 0..49 mark queried nodes; blocks 50..66 fold W12/bb ----
__global__ void k_mark_w12(const int* __restrict__ inp, unsigned char* __restrict__ mark,
                           unsigned char* __restrict__ need2,
                           const float* __restrict__ W1, const float* __restrict__ W2,
                           const float* __restrict__ b1, float* __restrict__ W12,
                           float* __restrict__ bb) {
    if (blockIdx.x < 50) {
        int t = blockIdx.x * 256 + threadIdx.x;
        if (t < NBL) { int n = inp[t]; mark[n] = 1; need2[n] = 1; }
    } else {
        int id = (blockIdx.x - 50) * 256 + threadIdx.x;
        if (id < 64 * 64) {
            int i = id >> 6, j = id & 63;
            float acc = 0.f;
            for (int k = 0; k < 128; ++k) acc += W1[i * 128 + k] * W2[k * 64 + j];
            W12[id] = acc;
        } else if (id < 64 * 64 + 64) {
            int j = id - 64 * 64;
            float acc = 0.f;
            for (int k = 0; k < 128; ++k) acc += b1[k] * W2[k * 64 + j];
            bb[j] = acc;
        }
    }
}

// ---- K2 (512 thr): blocks 0..NCHK-1 per-chunk LDS bucket sort (no global atomics);
//      blocks NCHK.. : emb fp32->bf16 streaming convert (overlapped) ----
__global__ __launch_bounds__(512) void k_bucket(
        const int* __restrict__ src, const int* __restrict__ dst,
        int* __restrict__ E, int* __restrict__ loffT,
        const unsigned char* __restrict__ mark, unsigned char* __restrict__ need2,
        const float* __restrict__ emb, ushortT* __restrict__ embH) {
    __shared__ int sv[CHUNK];
    __shared__ int h[NBKT];
    __shared__ int loff[NBKT];
    __shared__ int cur[NBKT];
    int t = threadIdx.x;
    int c = blockIdx.x;
    if (c >= NCHK) {                        // convert block: pure streaming
        int id = (c - NCHK) * 512 + t;      // NCONV*512 == NTOKEN*NINP/4 exactly
        float4 v = ((const float4*)emb)[id];
        ushort4 hh;
        hh.x = f2b(v.x); hh.y = f2b(v.y); hh.z = f2b(v.z); hh.w = f2b(v.w);
        ((ushort4*)embH)[id] = hh;
        return;
    }
    int base = c * CHUNK;
    int cnt = NEDGE - base; if (cnt > CHUNK) cnt = CHUNK;

    h[t] = 0; cur[t] = 0;
    __syncthreads();
    for (int j = t; j < cnt; j += 512)
        atomicAdd(&h[(unsigned)dst[base + j] / NPB], 1);
    __syncthreads();
    loff[t] = h[t];
    __syncthreads();
    scan512b(loff);                         // inclusive
    int excl = loff[t] - h[t];
    loffT[c * LROW + t] = excl;             // coalesced (chunk-major)
    if (t == 0) loffT[c * LROW + 512] = cnt;
    loff[t] = excl;
    __syncthreads();
    for (int j = t; j < cnt; j += 512) {
        unsigned d = (unsigned)dst[base + j];
        unsigned bk = d / NPB;
        int s = src[base + j];
        if (mark[d]) need2[s] = 1;          // layer-2 frontier expansion, fused
        int packed = (int)(((d - bk * NPB) << 18) | (unsigned)s);
        int pl = atomicAdd(&cur[bk], 1);
        sv[loff[bk] + pl] = packed;
    }
    __syncthreads();
    for (int j = t; j < cnt; j += 512)
        E[base + j] = sv[j];                // fully coalesced, own chunk slot
}

// ---- K3 (512 thr): per-bucket segment-gather + CSR + dinv/rows/nlist ----
__global__ __launch_bounds__(512) void k_csr(
        const int* __restrict__ E, const int* __restrict__ loffT,
        const unsigned char* __restrict__ need2,
        int* __restrict__ csr, float* __restrict__ dinv,
        int2* __restrict__ rows, int* __restrict__ nlist, int* __restrict__ ncnt) {
    __shared__ int eL[CAPB];
    __shared__ int csrL[CAPB];
    __shared__ int cnt[NBKT];
    __shared__ int off[NBKT];
    __shared__ int cur[NBKT];
    __shared__ int sgS[NBKT];
    __shared__ int sgL[NBKT];
    __shared__ unsigned char n2[NPB];
    __shared__ int nl[NPB];
    __shared__ int lcnt, nbase;
    int t = threadIdx.x;
    int b = blockIdx.x;
    int nodes = NTOKEN - b * NPB; if (nodes > NPB) nodes = NPB;

    cnt[t] = 0;
    if (t == 0) lcnt = 0;
    if (t < nodes) n2[t] = need2[b * NPB + t];
    {
        int s = 0, l = 0;
        if (t < NCHK) {
            s = loffT[t * LROW + b];
            l = loffT[t * LROW + b + 1] - s;
            s += t * CHUNK;
        }
        sgS[t] = s; sgL[t] = l; off[t] = l;
    }
    __syncthreads();
    scan512b(off);                          // inclusive over segment lengths
    int n = off[NBKT - 1];
    {
        int o = off[t] - sgL[t];
        int s = sgS[t];
        int l = sgL[t];
        for (int k = 0; k < l; ++k)
            eL[o + k] = E[s + k];           // one chunk-segment per thread
    }
    __syncthreads();
    for (int j = t; j < n; j += 512)
        atomicAdd(&cnt[eL[j] >> 18], 1);
    __syncthreads();
    off[t] = cnt[t];
    __syncthreads();
    scan512b(off);                          // inclusive per-node counts
    int cbase = b * CAPB;
    if (t < nodes) {
        int node = b * NPB + t;
        dinv[node] = rsqrtf((float)(cnt[t] + 1));
        rows[node] = make_int2(cbase + off[t] - cnt[t], cbase + off[t]);
        if (n2[t]) nl[atomicAdd(&lcnt, 1)] = node;
    }
    cur[t] = off[t] - cnt[t];
    __syncthreads();
    if (t == 0) nbase = lcnt ? atomicAdd(ncnt, lcnt) : 0;
    __syncthreads();
    if (t < lcnt) nlist[nbase + t] = nl[t];
    for (int j = t; j < n; j += 512) {      // selective placement: needed rows only
        int v = eL[j];
        int node = v >> 18;
        if (!n2[node]) continue;
        int pos = atomicAdd(&cur[node], 1);
        csrL[pos] = v & 0x3FFFF;
    }
    __syncthreads();
    for (int j = t; j < n; j += 512)
        csr[cbase + j] = csrL[j];
}

// ---- quad-row gather: 4 edges per load instruction; returns per-qf float4 sums,
//      edge-weight sum in *sw. Lanes: qf=lane&15 (feature quad), qe=lane>>4 (edge slot).
__device__ __forceinline__ float4 quad_gather(const ushortT* __restrict__ tab,
                                              const int* __restrict__ csr,
                                              const float* __restrict__ dinv,
                                              int b, int deg, int lane, int qe, int qf,
                                              int myE, float myW, float* sw) {
    float ax0 = 0.f, ay0 = 0.f, az0 = 0.f, aw0 = 0.f;
    float ax1 = 0.f, ay1 = 0.f, az1 = 0.f, aw1 = 0.f;
    float ws = 0.f;
    int base = 0;
    while (base < deg) {
        int m = deg - base; if (m > 64) m = 64;
        for (int e = 0; e < m; e += 8) {
            int   sA = __shfl(myE, e + qe);
            float wA = __shfl(myW, e + qe);
            int   sB = __shfl(myE, e + 4 + qe);
            float wB = __shfl(myW, e + 4 + qe);
            uint2 vA = *(const uint2*)(tab + sA * NINP + qf * 4);
            uint2 vB = *(const uint2*)(tab + sB * NINP + qf * 4);
            ax0 += wA * __uint_as_float(vA.x << 16);
            ay0 += wA * __uint_as_float(vA.x & 0xffff0000u);
            az0 += wA * __uint_as_float(vA.y << 16);
            aw0 += wA * __uint_as_float(vA.y & 0xffff0000u);
            ax1 += wB * __uint_as_float(vB.x << 16);
            ay1 += wB * __uint_as_float(vB.x & 0xffff0000u);
            az1 += wB * __uint_as_float(vB.y << 16);
            aw1 += wB * __uint_as_float(vB.y & 0xffff0000u);
            ws  += wA + wB;
        }
        base += 64;
        if (base >= deg) break;
        int mm = deg - base; if (mm > 64) mm = 64;
        myE = 0; myW = 0.f;
        if (lane < mm) { myE = csr[b + base + lane]; myW = dinv[myE]; }
    }
    float4 r;
    r.x = ax0 + ax1; r.y = ay0 + ay1; r.z = az0 + az1; r.w = aw0 + aw1;
    r.x += __shfl_xor(r.x, 16); r.y += __shfl_xor(r.y, 16);
    r.z += __shfl_xor(r.z, 16); r.w += __shfl_xor(r.w, 16);
    r.x += __shfl_xor(r.x, 32); r.y += __shfl_xor(r.y, 32);
    r.z += __shfl_xor(r.z, 32); r.w += __shfl_xor(r.w, 32);
    ws += __shfl_xor(ws, 16); ws += __shfl_xor(ws, 32);
    *sw = ws;
    return r;
}

// ---- K4: layer-1 gather, two nodes per wave iteration, quad-row loads ----
__global__ void k_gather1(const int* __restrict__ nlist, const int* __restrict__ ncnt,
                          const int2* __restrict__ rows, const int* __restrict__ csr,
                          const float* __restrict__ dinv, const ushortT* __restrict__ embH,
                          ushortT* __restrict__ P1H) {
    int lane = threadIdx.x & 63;
    int qe = lane >> 4, qf = lane & 15;
    int wid = blockIdx.x * (blockDim.x >> 6) + (threadIdx.x >> 6);
    int nw  = gridDim.x * (blockDim.x >> 6);
    int ncount = *ncnt;
    for (int p = wid; 2 * p < ncount; p += nw) {
        int i0 = nlist[2 * p];
        bool has1 = (2 * p + 1 < ncount);
        int i1 = has1 ? nlist[2 * p + 1] : i0;
        int2 r0 = rows[i0];
        int2 r1 = rows[i1];
        int b0 = r0.x, d0 = r0.y - r0.x;
        int b1 = r1.x, d1 = has1 ? (r1.y - r1.x) : 0;
        float di0 = dinv[i0];
        float di1 = dinv[i1];
        int m0 = d0 > 64 ? 64 : d0;
        int m1 = d1 > 64 ? 64 : d1;
        int e0 = 0; float w0 = 0.f;
        if (lane < m0) { e0 = csr[b0 + lane]; w0 = dinv[e0]; }
        int e1 = 0; float w1 = 0.f;
        if (lane < m1) { e1 = csr[b1 + lane]; w1 = dinv[e1]; }
        float sw0, sw1;
        float4 g0 = quad_gather(embH, csr, dinv, b0, d0, lane, qe, qf, e0, w0, &sw0);
        float4 g1 = quad_gather(embH, csr, dinv, b1, d1, lane, qe, qf, e1, w1, &sw1);
        if (qe == 0) {
            uint2 sv0 = *(const uint2*)(embH + i0 * NINP + qf * 4);
            ushort4 o0;
            o0.x = f2b(di0 * (di0 * __uint_as_float(sv0.x << 16)         + g0.x));
            o0.y = f2b(di0 * (di0 * __uint_as_float(sv0.x & 0xffff0000u) + g0.y));
            o0.z = f2b(di0 * (di0 * __uint_as_float(sv0.y << 16)         + g0.z));
            o0.w = f2b(di0 * (di0 * __uint_as_float(sv0.y & 0xffff0000u) + g0.w));
            *(ushort4*)(P1H + i0 * NINP + qf * 4) = o0;
            if (has1) {
                uint2 sv1 = *(const uint2*)(embH + i1 * NINP + qf * 4);
                ushort4 o1;
                o1.x = f2b(di1 * (di1 * __uint_as_float(sv1.x << 16)         + g1.x));
                o1.y = f2b(di1 * (di1 * __uint_as_float(sv1.x & 0xffff0000u) + g1.y));
                o1.z = f2b(di1 * (di1 * __uint_as_float(sv1.y << 16)         + g1.z));
                o1.w = f2b(di1 * (di1 * __uint_as_float(sv1.y & 0xffff0000u) + g1.w));
                *(ushort4*)(P1H + i1 * NINP + qf * 4) = o1;
            }
        }
    }
}

// ---- K5: final layer-2 quad gather + 64x64 GEMM + biases ----
__global__ void k_final(const int* __restrict__ inp, const int2* __restrict__ rows,
                        const int* __restrict__ csr, const float* __restrict__ dinv,
                        const ushortT* __restrict__ P1H, const float* __restrict__ W12,
                        const float* __restrict__ bb, const float* __restrict__ b2,
                        float* __restrict__ out) {
    int t = blockIdx.x * 4 + (threadIdx.x >> 6);
    if (t >= NBL) return;
    int lane = threadIdx.x & 63;
    int qe = lane >> 4, qf = lane & 15;
    int n = inp[t];
    float dn = dinv[n];
    int2 rn = rows[n];
    int b = rn.x;
    int deg = rn.y - rn.x;
    int m = deg > 64 ? 64 : deg;
    int myE = 0; float myW = 0.f;
    if (lane < m) { myE = csr[b + lane]; myW = dinv[myE]; }
    float sw;
    float4 g = quad_gather(P1H, csr, dinv, b, deg, lane, qe, qf, myE, myW, &sw);
    uint2 sv = *(const uint2*)(P1H + n * NINP + qf * 4);
    float4 p2;
    p2.x = dn * (dn * __uint_as_float(sv.x << 16)         + g.x);
    p2.y = dn * (dn * __uint_as_float(sv.x & 0xffff0000u) + g.y);
    p2.z = dn * (dn * __uint_as_float(sv.y << 16)         + g.z);
    p2.w = dn * (dn * __uint_as_float(sv.y & 0xffff0000u) + g.w);
    float sS = dn + sw;
    float acc = b2[lane] + dn * sS * bb[lane];
#pragma unroll
    for (int q = 0; q < 16; ++q) {
        float px = __shfl(p2.x, q), py = __shfl(p2.y, q);
        float pz = __shfl(p2.z, q), pw = __shfl(p2.w, q);
        acc += px * W12[(4 * q + 0) * 64 + lane] + py * W12[(4 * q + 1) * 64 + lane]
             + pz * W12[(4 * q + 2) * 64 + lane] + pw * W12[(4 * q + 3) * 64 + lane];
    }
    out[t * 64 + lane] = acc;
}

extern "C" void kernel_launch(void* const* d_in, const int* in_sizes, int n_in,
                              void* d_out, int out_size, void* d_ws, size_t ws_size,
                              hipStream_t stream) {
    const int*   inp  = (const int*)d_in[0];
    const int*   eidx = (const int*)d_in[3];
    const int*   esrc = eidx;
    const int*   edst = eidx + NEDGE;
    const float* emb  = (const float*)d_in[4];
    const float* W1   = (const float*)d_in[5];
    const float* b1   = (const float*)d_in[6];
    const float* W2   = (const float*)d_in[7];
    const float* b2   = (const float*)d_in[8];
    float* out = (float*)d_out;

    char* ws = (char*)d_ws;
    int*           ncnt   = (int*)(ws + 0);            //         4
    unsigned char* mark   = (unsigned char*)(ws + 4096);      // 200,000
    unsigned char* need2  = (unsigned char*)(ws + 204096);    // 200,000
    int2*          rows   = (int2*)(ws + 404096);      //  1,600,000
    float*         dinv   = (float*)(ws + 2004096);    //    800,000
    int*           nlist  = (int*)(ws + 2804096);      //    800,000
    int*           csr    = (int*)(ws + 3604096);      // 12,582,912
    float*         W12    = (float*)(ws + 16187008);   //     16,384
    float*         bb     = (float*)(ws + 16203392);   //        256
    ushortT*       embH   = (ushortT*)(ws + 16203648); // 25,600,000
    ushortT*       P1H    = (ushortT*)(ws + 41803648); // 25,600,000 (end 67,403,648)
    // E + loffT alias the P1H region: both dead before P1H is first written
    int*           E      = (int*)(ws + 41803648);     //  8,011,776
    int*           loffT  = (int*)(ws + 49815424);     //  1,003,428

    const int B = 256;

    k_zero    <<<(404096 / 4 + B - 1) / B, B, 0, stream>>>((int*)ws);
    k_mark_w12<<<67, B, 0, stream>>>(inp, mark, need2, W1, W2, b1, W12, bb);
    k_bucket  <<<NCHK + NCONV, 512, 0, stream>>>(esrc, edst, E, loffT, mark, need2, emb, embH);
    k_csr     <<<NBKT, 512, 0, stream>>>(E, loffT, need2, csr, dinv, rows, nlist, ncnt);

    k_gather1 <<<2048, B, 0, stream>>>(nlist, ncnt, rows, csr, dinv, embH, P1H);
    k_final   <<<(NBL + 3) / 4, B, 0, stream>>>(inp, rows, csr, dinv, P1H, W12, bb, b2, out);
}

// Round 15
// 108.010 us; speedup vs baseline: 1.4425x; 1.0181x over previous
//
#include <hip/hip_runtime.h>

#define NTOKEN 200000
#define NINP   64
#define NEDGE  2000000
#define NBL    12800
#define NBKT   512
#define NPB    391            // nodes per bucket
#define CHUNK  4096
#define NCHK   ((NEDGE + CHUNK - 1) / CHUNK)   // 489
#define LROW   (NBKT + 1)                      // 513 ints per chunk in loffT
#define CAPB   6144           // per-bucket capacity (mean 3906, ~36 sigma headroom)
#define NCONV  6250           // emb-convert blocks at 512 thr (6250*512*4 == NTOKEN*NINP)

typedef unsigned short ushortT;

#define B2F(h) __uint_as_float(((unsigned)(h)) << 16)
__device__ __forceinline__ ushortT f2b(float x) {
    unsigned u = __float_as_uint(x);
    return (ushortT)((u + 0x7FFFu + ((u >> 16) & 1u)) >> 16);   // RNE
}

// ---- inclusive scan over s[0..511], 512 threads, caller syncs before ----
__device__ __forceinline__ void scan512b(int* s) {
    int t = threadIdx.x;
    for (int d = 1; d < 512; d <<= 1) {
        int v = (t >= d) ? s[t - d] : 0;
        __syncthreads();
        s[t] += v;
        __syncthreads();
    }
}

// ---- K0: zero ncnt+mark+need2 (404,096 B as ints) ----
__global__ void k_zero(int* __restrict__ z) {
    int i = blockIdx.x * blockDim.x + threadIdx.x;
    if (i < 404096 / 4) z[i] = 0;
}

// ---- K1: blocks 0..49 mark queried nodes; blocks 50..66 fold W12/bb ----
__global__ void k_mark_w12(const int* __restrict__ inp, unsigned char* __restrict__ mark,
                           unsigned char* __restrict__ need2,
                           const float* __restrict__ W1, const float* __restrict__ W2,
                           const float* __restrict__ b1, float* __restrict__ W12,
                           float* __restrict__ bb) {
    if (blockIdx.x < 50) {
        int t = blockIdx.x * 256 + threadIdx.x;
        if (t < NBL) { int n = inp[t]; mark[n] = 1; need2[n] = 1; }
    } else {
        int id = (blockIdx.x - 50) * 256 + threadIdx.x;
        if (id < 64 * 64) {
            int i = id >> 6, j = id & 63;
            float acc = 0.f;
            for (int k = 0; k < 128; ++k) acc += W1[i * 128 + k] * W2[k * 64 + j];
            W12[id] = acc;
        } else if (id < 64 * 64 + 64) {
            int j = id - 64 * 64;
            float acc = 0.f;
            for (int k = 0; k < 128; ++k) acc += b1[k] * W2[k * 64 + j];
            bb[j] = acc;
        }
    }
}

// ---- K2 (512 thr): blocks 0..NCHK-1 per-chunk LDS bucket sort (no global atomics);
//      blocks NCHK.. : emb fp32->bf16 streaming convert (overlapped) ----
__global__ __launch_bounds__(512) void k_bucket(
        const int* __restrict__ src, const int* __restrict__ dst,
        int* __restrict__ E, int* __restrict__ loffT,
        const unsigned char* __restrict__ mark, unsigned char* __restrict__ need2,
        const float* __restrict__ emb, ushortT* __restrict__ embH) {
    __shared__ int sv[CHUNK];
    __shared__ int h[NBKT];
    __shared__ int loff[NBKT];
    __shared__ int cur[NBKT];
    int t = threadIdx.x;
    int c = blockIdx.x;
    if (c >= NCHK) {                        // convert block: pure streaming
        int id = (c - NCHK) * 512 + t;      // NCONV*512 == NTOKEN*NINP/4 exactly
        float4 v = ((const float4*)emb)[id];
        ushort4 hh;
        hh.x = f2b(v.x); hh.y = f2b(v.y); hh.z = f2b(v.z); hh.w = f2b(v.w);
        ((ushort4*)embH)[id] = hh;
        return;
    }
    int base = c * CHUNK;
    int cnt = NEDGE - base; if (cnt > CHUNK) cnt = CHUNK;

    h[t] = 0; cur[t] = 0;
    __syncthreads();
    for (int j = t; j < cnt; j += 512)
        atomicAdd(&h[(unsigned)dst[base + j] / NPB], 1);
    __syncthreads();
    loff[t] = h[t];
    __syncthreads();
    scan512b(loff);                         // inclusive
    int excl = loff[t] - h[t];
    loffT[c * LROW + t] = excl;             // coalesced (chunk-major)
    if (t == 0) loffT[c * LROW + 512] = cnt;
    loff[t] = excl;
    __syncthreads();
    for (int j = t; j < cnt; j += 512) {
        unsigned d = (unsigned)dst[base + j];
        unsigned bk = d / NPB;
        int s = src[base + j];
        if (mark[d]) need2[s] = 1;          // layer-2 frontier expansion, fused
        int packed = (int)(((d - bk * NPB) << 18) | (unsigned)s);
        int pl = atomicAdd(&cur[bk], 1);
        sv[loff[bk] + pl] = packed;
    }
    __syncthreads();
    for (int j = t; j < cnt; j += 512)
        E[base + j] = sv[j];                // fully coalesced, own chunk slot
}

// ---- K3 (512 thr): per-bucket segment-gather + CSR + dinv/rows/nlist ----
__global__ __launch_bounds__(512) void k_csr(
        const int* __restrict__ E, const int* __restrict__ loffT,
        const unsigned char* __restrict__ need2,
        int* __restrict__ csr, float* __restrict__ dinv,
        int2* __restrict__ rows, int* __restrict__ nlist, int* __restrict__ ncnt) {
    __shared__ int eL[CAPB];
    __shared__ int csrL[CAPB];
    __shared__ int cnt[NBKT];
    __shared__ int off[NBKT];
    __shared__ int cur[NBKT];
    __shared__ int sgS[NBKT];
    __shared__ int sgL[NBKT];
    __shared__ unsigned char n2[NPB];
    __shared__ int nl[NPB];
    __shared__ int lcnt, nbase;
    int t = threadIdx.x;
    int b = blockIdx.x;
    int nodes = NTOKEN - b * NPB; if (nodes > NPB) nodes = NPB;

    cnt[t] = 0;
    if (t == 0) lcnt = 0;
    if (t < nodes) n2[t] = need2[b * NPB + t];
    {
        int s = 0, l = 0;
        if (t < NCHK) {
            s = loffT[t * LROW + b];
            l = loffT[t * LROW + b + 1] - s;
            s += t * CHUNK;
        }
        sgS[t] = s; sgL[t] = l; off[t] = l;
    }
    __syncthreads();
    scan512b(off);                          // inclusive over segment lengths
    int n = off[NBKT - 1];
    {
        int o = off[t] - sgL[t];
        int s = sgS[t];
        int l = sgL[t];
        for (int k = 0; k < l; ++k)
            eL[o + k] = E[s + k];           // one chunk-segment per thread
    }
    __syncthreads();
    for (int j = t; j < n; j += 512)
        atomicAdd(&cnt[eL[j] >> 18], 1);
    __syncthreads();
    off[t] = cnt[t];
    __syncthreads();
    scan512b(off);                          // inclusive per-node counts
    int cbase = b * CAPB;
    if (t < nodes) {
        int node = b * NPB + t;
        dinv[node] = rsqrtf((float)(cnt[t] + 1));
        rows[node] = make_int2(cbase + off[t] - cnt[t], cbase + off[t]);
        if (n2[t]) nl[atomicAdd(&lcnt, 1)] = node;
    }
    cur[t] = off[t] - cnt[t];
    __syncthreads();
    if (t == 0) nbase = lcnt ? atomicAdd(ncnt, lcnt) : 0;
    __syncthreads();
    if (t < lcnt) nlist[nbase + t] = nl[t];
    for (int j = t; j < n; j += 512) {      // selective placement: needed rows only
        int v = eL[j];
        int node = v >> 18;
        if (!n2[node]) continue;
        int pos = atomicAdd(&cur[node], 1);
        csrL[pos] = v & 0x3FFFF;
    }
    __syncthreads();
    for (int j = t; j < n; j += 512)
        csr[cbase + j] = csrL[j];
}

// ---- single-node tail batch (deg>64, rare): groups of 8 edges ----
#define TAIL_GATHER(bN, dN, myEN, myWN, AX, AY, AZ, AW, WS)                         \
    for (int base = 64; base < dN; base += 64) {                                    \
        int mm = dN - base; if (mm > 64) mm = 64;                                   \
        int tE = 0; float tW = 0.f;                                                 \
        if (lane < mm) { tE = csr[bN + base + lane]; tW = dinv[tE]; }               \
        for (int e = 0; e < mm; e += 8) {                                           \
            int   sA = __shfl(tE, e + qe);     float wA = __shfl(tW, e + qe);       \
            int   sB = __shfl(tE, e + 4 + qe); float wB = __shfl(tW, e + 4 + qe);   \
            uint2 vA = *(const uint2*)(tab + sA * NINP + qf * 4);                   \
            uint2 vB = *(const uint2*)(tab + sB * NINP + qf * 4);                   \
            AX += wA * __uint_as_float(vA.x << 16) + wB * __uint_as_float(vB.x << 16);          \
            AY += wA * __uint_as_float(vA.x & 0xffff0000u) + wB * __uint_as_float(vB.x & 0xffff0000u); \
            AZ += wA * __uint_as_float(vA.y << 16) + wB * __uint_as_float(vB.y << 16);          \
            AW += wA * __uint_as_float(vA.y & 0xffff0000u) + wB * __uint_as_float(vB.y & 0xffff0000u); \
            WS += wA + wB;                                                          \
        }                                                                           \
    }

// ---- pair gather: two nodes' quad-row gathers interleaved (4 loads in flight) ----
__device__ __forceinline__ void pair_gather(const ushortT* __restrict__ tab,
                                            const int* __restrict__ csr,
                                            const float* __restrict__ dinv,
                                            int b0, int d0, int b1, int d1,
                                            int lane, int qe, int qf,
                                            int myE0, float myW0, int myE1, float myW1,
                                            float4* g0, float4* g1,
                                            float* sw0, float* sw1) {
    float x0 = 0.f, y0 = 0.f, z0 = 0.f, w0a = 0.f, ws0 = 0.f;
    float x1 = 0.f, y1 = 0.f, z1 = 0.f, w1a = 0.f, ws1 = 0.f;
    int m0 = d0 > 64 ? 64 : d0;
    int m1 = d1 > 64 ? 64 : d1;
    int mx = m0 > m1 ? m0 : m1;
    for (int e = 0; e < mx; e += 8) {
        int   sA0 = __shfl(myE0, e + qe);     float wA0 = __shfl(myW0, e + qe);
        int   sB0 = __shfl(myE0, e + 4 + qe); float wB0 = __shfl(myW0, e + 4 + qe);
        int   sA1 = __shfl(myE1, e + qe);     float wA1 = __shfl(myW1, e + qe);
        int   sB1 = __shfl(myE1, e + 4 + qe); float wB1 = __shfl(myW1, e + 4 + qe);
        uint2 vA0 = *(const uint2*)(tab + sA0 * NINP + qf * 4);
        uint2 vB0 = *(const uint2*)(tab + sB0 * NINP + qf * 4);
        uint2 vA1 = *(const uint2*)(tab + sA1 * NINP + qf * 4);
        uint2 vB1 = *(const uint2*)(tab + sB1 * NINP + qf * 4);
        x0  += wA0 * __uint_as_float(vA0.x << 16)         + wB0 * __uint_as_float(vB0.x << 16);
        y0  += wA0 * __uint_as_float(vA0.x & 0xffff0000u) + wB0 * __uint_as_float(vB0.x & 0xffff0000u);
        z0  += wA0 * __uint_as_float(vA0.y << 16)         + wB0 * __uint_as_float(vB0.y << 16);
        w0a += wA0 * __uint_as_float(vA0.y & 0xffff0000u) + wB0 * __uint_as_float(vB0.y & 0xffff0000u);
        ws0 += wA0 + wB0;
        x1  += wA1 * __uint_as_float(vA1.x << 16)         + wB1 * __uint_as_float(vB1.x << 16);
        y1  += wA1 * __uint_as_float(vA1.x & 0xffff0000u) + wB1 * __uint_as_float(vB1.x & 0xffff0000u);
        z1  += wA1 * __uint_as_float(vA1.y << 16)         + wB1 * __uint_as_float(vB1.y << 16);
        w1a += wA1 * __uint_as_float(vA1.y & 0xffff0000u) + wB1 * __uint_as_float(vB1.y & 0xffff0000u);
        ws1 += wA1 + wB1;
    }
    if (d0 > 64) { TAIL_GATHER(b0, d0, myE0, myW0, x0, y0, z0, w0a, ws0) }
    if (d1 > 64) { TAIL_GATHER(b1, d1, myE1, myW1, x1, y1, z1, w1a, ws1) }
    x0  += __shfl_xor(x0, 16);  x0  += __shfl_xor(x0, 32);
    y0  += __shfl_xor(y0, 16);  y0  += __shfl_xor(y0, 32);
    z0  += __shfl_xor(z0, 16);  z0  += __shfl_xor(z0, 32);
    w0a += __shfl_xor(w0a, 16); w0a += __shfl_xor(w0a, 32);
    ws0 += __shfl_xor(ws0, 16); ws0 += __shfl_xor(ws0, 32);
    x1  += __shfl_xor(x1, 16);  x1  += __shfl_xor(x1, 32);
    y1  += __shfl_xor(y1, 16);  y1  += __shfl_xor(y1, 32);
    z1  += __shfl_xor(z1, 16);  z1  += __shfl_xor(z1, 32);
    w1a += __shfl_xor(w1a, 16); w1a += __shfl_xor(w1a, 32);
    ws1 += __shfl_xor(ws1, 16); ws1 += __shfl_xor(ws1, 32);
    *g0 = make_float4(x0, y0, z0, w0a);
    *g1 = make_float4(x1, y1, z1, w1a);
    *sw0 = ws0; *sw1 = ws1;
}

// ---- K4: layer-1 gather, two nodes per wave iteration, interleaved pair gather ----
__global__ void k_gather1(const int* __restrict__ nlist, const int* __restrict__ ncnt,
                          const int2* __restrict__ rows, const int* __restrict__ csr,
                          const float* __restrict__ dinv, const ushortT* __restrict__ embH,
                          ushortT* __restrict__ P1H) {
    int lane = threadIdx.x & 63;
    int qe = lane >> 4, qf = lane & 15;
    int wid = blockIdx.x * (blockDim.x >> 6) + (threadIdx.x >> 6);
    int nw  = gridDim.x * (blockDim.x >> 6);
    int ncount = *ncnt;
    for (int p = wid; 2 * p < ncount; p += nw) {
        int i0 = nlist[2 * p];
        bool has1 = (2 * p + 1 < ncount);
        int i1 = has1 ? nlist[2 * p + 1] : i0;
        int2 r0 = rows[i0];
        int2 r1 = rows[i1];
        int b0 = r0.x, d0 = r0.y - r0.x;
        int b1 = r1.x, d1 = has1 ? (r1.y - r1.x) : 0;
        float di0 = rsqrtf((float)(d0 + 1));        // == dinv[i0], recomputed
        float di1 = rsqrtf((float)(d1 + 1));
        int m0 = d0 > 64 ? 64 : d0;
        int m1 = d1 > 64 ? 64 : d1;
        int e0 = 0; float w0 = 0.f;
        if (lane < m0) { e0 = csr[b0 + lane]; w0 = dinv[e0]; }
        int e1 = 0; float w1 = 0.f;
        if (lane < m1) { e1 = csr[b1 + lane]; w1 = dinv[e1]; }
        float4 g0, g1; float sw0, sw1;
        pair_gather(embH, csr, dinv, b0, d0, b1, d1, lane, qe, qf,
                    e0, w0, e1, w1, &g0, &g1, &sw0, &sw1);
        if (qe == 0) {
            uint2 sv0 = *(const uint2*)(embH + i0 * NINP + qf * 4);
            ushort4 o0;
            o0.x = f2b(di0 * (di0 * __uint_as_float(sv0.x << 16)         + g0.x));
            o0.y = f2b(di0 * (di0 * __uint_as_float(sv0.x & 0xffff0000u) + g0.y));
            o0.z = f2b(di0 * (di0 * __uint_as_float(sv0.y << 16)         + g0.z));
            o0.w = f2b(di0 * (di0 * __uint_as_float(sv0.y & 0xffff0000u) + g0.w));
            *(ushort4*)(P1H + i0 * NINP + qf * 4) = o0;
            if (has1) {
                uint2 sv1 = *(const uint2*)(embH + i1 * NINP + qf * 4);
                ushort4 o1;
                o1.x = f2b(di1 * (di1 * __uint_as_float(sv1.x << 16)         + g1.x));
                o1.y = f2b(di1 * (di1 * __uint_as_float(sv1.x & 0xffff0000u) + g1.y));
                o1.z = f2b(di1 * (di1 * __uint_as_float(sv1.y << 16)         + g1.z));
                o1.w = f2b(di1 * (di1 * __uint_as_float(sv1.y & 0xffff0000u) + g1.w));
                *(ushort4*)(P1H + i1 * NINP + qf * 4) = o1;
            }
        }
    }
}

// ---- K5: final layer-2 gather (pairing two tokens per wave) + 64x64 GEMM + biases ----
__global__ void k_final(const int* __restrict__ inp, const int2* __restrict__ rows,
                        const int* __restrict__ csr, const float* __restrict__ dinv,
                        const ushortT* __restrict__ P1H, const float* __restrict__ W12,
                        const float* __restrict__ bb, const float* __restrict__ b2,
                        float* __restrict__ out) {
    int t0 = (blockIdx.x * 4 + (threadIdx.x >> 6)) * 2;
    if (t0 >= NBL) return;
    int lane = threadIdx.x & 63;
    int qe = lane >> 4, qf = lane & 15;
    int n0 = inp[t0];
    int n1 = inp[t0 + 1];                   // NBL even -> always valid
    int2 r0 = rows[n0];
    int2 r1 = rows[n1];
    int b0 = r0.x, d0 = r0.y - r0.x;
    int b1 = r1.x, d1 = r1.y - r1.x;
    float dn0 = rsqrtf((float)(d0 + 1));
    float dn1 = rsqrtf((float)(d1 + 1));
    int m0 = d0 > 64 ? 64 : d0;
    int m1 = d1 > 64 ? 64 : d1;
    int e0 = 0; float w0 = 0.f;
    if (lane < m0) { e0 = csr[b0 + lane]; w0 = dinv[e0]; }
    int e1 = 0; float w1 = 0.f;
    if (lane < m1) { e1 = csr[b1 + lane]; w1 = dinv[e1]; }
    float4 g0, g1; float sw0, sw1;
    pair_gather(P1H, csr, dinv, b0, d0, b1, d1, lane, qe, qf,
                e0, w0, e1, w1, &g0, &g1, &sw0, &sw1);
    uint2 sv0 = *(const uint2*)(P1H + n0 * NINP + qf * 4);
    uint2 sv1 = *(const uint2*)(P1H + n1 * NINP + qf * 4);
    float4 p0, p1;
    p0.x = dn0 * (dn0 * __uint_as_float(sv0.x << 16)         + g0.x);
    p0.y = dn0 * (dn0 * __uint_as_float(sv0.x & 0xffff0000u) + g0.y);
    p0.z = dn0 * (dn0 * __uint_as_float(sv0.y << 16)         + g0.z);
    p0.w = dn0 * (dn0 * __uint_as_float(sv0.y & 0xffff0000u) + g0.w);
    p1.x = dn1 * (dn1 * __uint_as_float(sv1.x << 16)         + g1.x);
    p1.y = dn1 * (dn1 * __uint_as_float(sv1.x & 0xffff0000u) + g1.y);
    p1.z = dn1 * (dn1 * __uint_as_float(sv1.y << 16)         + g1.z);
    p1.w = dn1 * (dn1 * __uint_as_float(sv1.y & 0xffff0000u) + g1.w);
    float sS0 = dn0 + sw0;
    float sS1 = dn1 + sw1;
    float bbl = bb[lane], b2l = b2[lane];
    float acc0 = b2l + dn0 * sS0 * bbl;
    float acc1 = b2l + dn1 * sS1 * bbl;
#pragma unroll
    for (int q = 0; q < 16; ++q) {
        float w0c = W12[(4 * q + 0) * 64 + lane];
        float w1c = W12[(4 * q + 1) * 64 + lane];
        float w2c = W12[(4 * q + 2) * 64 + lane];
        float w3c = W12[(4 * q + 3) * 64 + lane];
        acc0 += __shfl(p0.x, q) * w0c + __shfl(p0.y, q) * w1c
              + __shfl(p0.z, q) * w2c + __shfl(p0.w, q) * w3c;
        acc1 += __shfl(p1.x, q) * w0c + __shfl(p1.y, q) * w1c
              + __shfl(p1.z, q) * w2c + __shfl(p1.w, q) * w3c;
    }
    out[t0 * 64 + lane] = acc0;
    out[(t0 + 1) * 64 + lane] = acc1;
}

extern "C" void kernel_launch(void* const* d_in, const int* in_sizes, int n_in,
                              void* d_out, int out_size, void* d_ws, size_t ws_size,
                              hipStream_t stream) {
    const int*   inp  = (const int*)d_in[0];
    const int*   eidx = (const int*)d_in[3];
    const int*   esrc = eidx;
    const int*   edst = eidx + NEDGE;
    const float* emb  = (const float*)d_in[4];
    const float* W1   = (const float*)d_in[5];
    const float* b1   = (const float*)d_in[6];
    const float* W2   = (const float*)d_in[7];
    const float* b2   = (const float*)d_in[8];
    float* out = (float*)d_out;

    char* ws = (char*)d_ws;
    int*           ncnt   = (int*)(ws + 0);            //         4
    unsigned char* mark   = (unsigned char*)(ws + 4096);      // 200,000
    unsigned char* need2  = (unsigned char*)(ws + 204096);    // 200,000
    int2*          rows   = (int2*)(ws + 404096);      //  1,600,000
    float*         dinv   = (float*)(ws + 2004096);    //    800,000
    int*           nlist  = (int*)(ws + 2804096);      //    800,000
    int*           csr    = (int*)(ws + 3604096);      // 12,582,912
    float*         W12    = (float*)(ws + 16187008);   //     16,384
    float*         bb     = (float*)(ws + 16203392);   //        256
    ushortT*       embH   = (ushortT*)(ws + 16203648); // 25,600,000
    ushortT*       P1H    = (ushortT*)(ws + 41803648); // 25,600,000 (end 67,403,648)
    // E + loffT alias the P1H region: both dead before P1H is first written
    int*           E      = (int*)(ws + 41803648);     //  8,011,776
    int*           loffT  = (int*)(ws + 49815424);     //  1,003,428

    const int B = 256;

    k_zero    <<<(404096 / 4 + B - 1) / B, B, 0, stream>>>((int*)ws);
    k_mark_w12<<<67, B, 0, stream>>>(inp, mark, need2, W1, W2, b1, W12, bb);
    k_bucket  <<<NCHK + NCONV, 512, 0, stream>>>(esrc, edst, E, loffT, mark, need2, emb, embH);
    k_csr     <<<NBKT, 512, 0, stream>>>(E, loffT, need2, csr, dinv, rows, nlist, ncnt);

    k_gather1 <<<2048, B, 0, stream>>>(nlist, ncnt, rows, csr, dinv, embH, P1H);
    k_final   <<<(NBL / 2 + 3) / 4, B, 0, stream>>>(inp, rows, csr, dinv, P1H, W12, bb, b2, out);
}